// Round 1
// baseline (1724.803 us; speedup 1.0000x reference)
//
#include <hip/hip_runtime.h>

// Problem constants
#define BB 16
#define TT 32
#define NN 1024
#define DD 64
#define HH 64
#define BN 16384          // B*N
#define GH 128
#define RR 128
#define OO 32

__device__ __forceinline__ float f4c(const float4& v, int kk) {
  return kk == 0 ? v.x : kk == 1 ? v.y : kk == 2 ? v.z : v.w;
}

// ---------------------------------------------------------------------------
// GRU layer kernel. x: [BN][T*64] contiguous rows. Writes h_all [BN][T*64]
// (layer 0) and/or h_last [BN][64] (layer 1 -> gru_feat).
// Block = 256 threads = 4 waves; wave w handles 8 sequences; lane j = hidden j.
// ---------------------------------------------------------------------------
__global__ __launch_bounds__(256) void gru_kernel(
    const float* __restrict__ x,
    const float* __restrict__ Wih, const float* __restrict__ Whh,
    const float* __restrict__ bih, const float* __restrict__ bhh,
    float* __restrict__ h_all, float* __restrict__ h_last)
{
  __shared__ __align__(16) float sWih[64][192];   // transposed: [k][gate*64+j]
  __shared__ __align__(16) float sWhh[64][192];
  __shared__ __align__(16) float sH[32][64];      // hidden state per local seq

  const int tid = threadIdx.x;
  for (int idx = tid; idx < 192 * 64; idx += 256) {
    int r = idx >> 6, c = idx & 63;
    sWih[c][r] = Wih[idx];
    sWhh[c][r] = Whh[idx];
  }
  const int w  = tid >> 6;
  const int j  = tid & 63;
  const int w8 = w * 8;
  const int sbase = blockIdx.x * 32 + w8;

#pragma unroll
  for (int s = 0; s < 8; ++s) sH[w8 + s][j] = 0.0f;

  const float br  = bih[j]       + bhh[j];
  const float bz  = bih[64 + j]  + bhh[64 + j];
  const float bni = bih[128 + j];
  const float bnh = bhh[128 + j];

  __syncthreads();

  float h[8];
#pragma unroll
  for (int s = 0; s < 8; ++s) h[s] = 0.0f;

  const float* xrow = x + (size_t)sbase * (TT * 64);

#define LOADV(XV, HV, K0)                                                      \
  _Pragma("unroll")                                                            \
  for (int s = 0; s < 8; ++s) {                                                \
    XV[s] = *reinterpret_cast<const float4*>(xt0 + (size_t)s * (TT*64) + (K0));\
    HV[s] = *reinterpret_cast<const float4*>(&sH[w8 + s][(K0)]);               \
  }

#define COMPV(XV, HV, K0)                                                      \
  _Pragma("unroll")                                                            \
  for (int kk = 0; kk < 4; ++kk) {                                             \
    const int k = (K0) + kk;                                                   \
    const float wri = sWih[k][j], wzi = sWih[k][64 + j], wni = sWih[k][128 + j];\
    const float wrh = sWhh[k][j], wzh = sWhh[k][64 + j], wnh = sWhh[k][128 + j];\
    _Pragma("unroll")                                                          \
    for (int s = 0; s < 8; ++s) {                                              \
      const float xk = f4c(XV[s], kk);                                         \
      const float hk = f4c(HV[s], kk);                                         \
      ar[s]  = fmaf(wri, xk, ar[s]);  ar[s] = fmaf(wrh, hk, ar[s]);            \
      az[s]  = fmaf(wzi, xk, az[s]);  az[s] = fmaf(wzh, hk, az[s]);            \
      ani[s] = fmaf(wni, xk, ani[s]);                                          \
      anh[s] = fmaf(wnh, hk, anh[s]);                                          \
    }                                                                          \
  }

  for (int t = 0; t < TT; ++t) {
    float ar[8], az[8], ani[8], anh[8];
#pragma unroll
    for (int s = 0; s < 8; ++s) { ar[s] = br; az[s] = bz; ani[s] = bni; anh[s] = bnh; }

    const float* xt0 = xrow + t * 64;
    float4 xa[8], ha[8], xb[8], hb[8];
    LOADV(xa, ha, 0)
#pragma unroll 1
    for (int k0 = 0; k0 < 64; k0 += 8) {
      LOADV(xb, hb, k0 + 4)
      COMPV(xa, ha, k0)
      if (k0 + 8 < 64) { LOADV(xa, ha, k0 + 8) }
      COMPV(xb, hb, k0 + 4)
    }

#pragma unroll
    for (int s = 0; s < 8; ++s) {
      float r = 1.0f / (1.0f + __expf(-ar[s]));
      float z = 1.0f / (1.0f + __expf(-az[s]));
      float n = tanhf(ani[s] + r * anh[s]);
      h[s] = (1.0f - z) * n + z * h[s];
    }
#pragma unroll
    for (int s = 0; s < 8; ++s) sH[w8 + s][j] = h[s];
    if (h_all) {
#pragma unroll
      for (int s = 0; s < 8; ++s)
        h_all[(size_t)(sbase + s) * (TT*64) + t * 64 + j] = h[s];
    }
  }
  if (h_last) {
#pragma unroll
    for (int s = 0; s < 8; ++s)
      h_last[(size_t)(sbase + s) * 64 + j] = h[s];
  }
#undef LOADV
#undef COMPV
}

// ---------------------------------------------------------------------------
// GAT projection: Wh[i][hf] = sum_k feat[i][k]*gatW[k][hf];
// src/dst[i][h] = sum_f Wh[i][h][f]*a_src/dst[h][f].
// Block handles 8 rows.
// ---------------------------------------------------------------------------
__global__ __launch_bounds__(256) void gat_feat_kernel(
    const float* __restrict__ feat, const float* __restrict__ gatW,
    const float* __restrict__ a_src, const float* __restrict__ a_dst,
    float* __restrict__ Wh, float* __restrict__ srcv, float* __restrict__ dstv)
{
  __shared__ float sGatW[64 * 128];
  __shared__ float sFeat[8][64];
  __shared__ float sAs[128], sAd[128];
  const int tid = threadIdx.x;
  const int rowbase = blockIdx.x * 8;
  for (int idx = tid; idx < 8192; idx += 256) sGatW[idx] = gatW[idx];
  if (tid < 128) { sAs[tid] = a_src[tid]; sAd[tid] = a_dst[tid]; }
  for (int idx = tid; idx < 512; idx += 256)
    sFeat[idx >> 6][idx & 63] = feat[(size_t)rowbase * 64 + idx];
  __syncthreads();

  const int hf = tid & 127, half = tid >> 7;
  const int h = hf >> 5;
  const float as = sAs[hf], ad = sAd[hf];
  for (int rr = half; rr < 8; rr += 2) {
    float acc = 0.0f;
#pragma unroll 8
    for (int k = 0; k < 64; ++k) acc = fmaf(sFeat[rr][k], sGatW[k * 128 + hf], acc);
    const size_t grow = rowbase + rr;
    Wh[grow * 128 + hf] = acc;
    float ps = acc * as, pd = acc * ad;
#pragma unroll
    for (int m = 16; m >= 1; m >>= 1) {
      ps += __shfl_xor(ps, m, 32);
      pd += __shfl_xor(pd, m, 32);
    }
    if ((hf & 31) == 0) {
      srcv[grow * 4 + h] = ps;
      dstv[grow * 4 + h] = pd;
    }
  }
}

// ---------------------------------------------------------------------------
// Attention + gat aggregation. Block = (batch b, 32-row i-tile), 256 threads.
// Two-pass masked softmax (matches jax: masked logits = -1e9), writes attn
// [B,N,N,4] and gat (elu applied) [BN][128].
// ---------------------------------------------------------------------------
__global__ __launch_bounds__(256) void attn_kernel(
    const float* __restrict__ Wh, const float* __restrict__ srcp,
    const float* __restrict__ dstp, const int* __restrict__ adj,
    float* __restrict__ attn_out, float* __restrict__ gat_out)
{
  __shared__ __align__(16) float sDst[1024 * 4];
  __shared__ __align__(16) float sSrc[32 * 4];
  __shared__ __align__(16) float sM[128];
  __shared__ __align__(16) float sIS[128];
  __shared__ float sPart[2][256];
  __shared__ __align__(16) float sWh[64][4][36];   // padded: banks spread

  const int tid = threadIdx.x;
  const int b = blockIdx.x >> 5;
  const int itile = (blockIdx.x & 31) << 5;

  for (int idx = tid; idx < 4096; idx += 256) sDst[idx] = dstp[(size_t)b * 4096 + idx];
  if (tid < 128) sSrc[tid] = srcp[((size_t)b * 1024 + itile) * 4 + tid];
  __syncthreads();

  const int il = tid >> 3, hh = (tid >> 1) & 3, par = tid & 1;
  const int ih = il * 4 + hh;
  const int* adjrow = adj + (size_t)(itile + il) * 1024;
  {
    const float sv = sSrc[ih];
    float m = -1e30f;
    for (int jj = par; jj < 1024; jj += 2) {
      float e = sv + sDst[jj * 4 + hh];
      e = e > 0.0f ? e : 0.2f * e;
      float ev = adjrow[jj] ? e : -1e9f;
      m = fmaxf(m, ev);
    }
    float ssum = 0.0f;
    for (int jj = par; jj < 1024; jj += 2) {
      float e = sv + sDst[jj * 4 + hh];
      e = e > 0.0f ? e : 0.2f * e;
      float ev = adjrow[jj] ? e : -1e9f;
      ssum += __expf(ev - m);
    }
    sPart[par][ih * 2]     = m;
    sPart[par][ih * 2 + 1] = ssum;
  }
  __syncthreads();
  if (par == 0) {
    float m0 = sPart[0][ih * 2], s0 = sPart[0][ih * 2 + 1];
    float m1 = sPart[1][ih * 2], s1 = sPart[1][ih * 2 + 1];
    float m = fmaxf(m0, m1);
    float s = s0 * __expf(m0 - m) + s1 * __expf(m1 - m);
    sM[ih] = m;
    sIS[ih] = 1.0f / s;
  }
  __syncthreads();

  // ---- pass 2a: write attn (thread = (i, jsub), float4 over heads) ----
  {
    const int il_a = tid >> 3, jsub = tid & 7;
    const int* adjA = adj + (size_t)(itile + il_a) * 1024;
    const float4 sv4 = *reinterpret_cast<const float4*>(&sSrc[il_a * 4]);
    const float4 m4  = *reinterpret_cast<const float4*>(&sM[il_a * 4]);
    const float4 is4 = *reinterpret_cast<const float4*>(&sIS[il_a * 4]);
    float4* arow = reinterpret_cast<float4*>(
        attn_out + ((size_t)(b * 1024 + itile + il_a)) * 4096);
    for (int q = 0; q < 128; ++q) {
      const int jj = jsub + (q << 3);
      const int av = adjA[jj];
      const float4 dv = *reinterpret_cast<const float4*>(&sDst[jj * 4]);
      float4 a4;
      float e;
      e = sv4.x + dv.x; e = e > 0.f ? e : 0.2f * e; a4.x = __expf((av ? e : -1e9f) - m4.x) * is4.x;
      e = sv4.y + dv.y; e = e > 0.f ? e : 0.2f * e; a4.y = __expf((av ? e : -1e9f) - m4.y) * is4.y;
      e = sv4.z + dv.z; e = e > 0.f ? e : 0.2f * e; a4.z = __expf((av ? e : -1e9f) - m4.z) * is4.z;
      e = sv4.w + dv.w; e = e > 0.f ? e : 0.2f * e; a4.w = __expf((av ? e : -1e9f) - m4.w) * is4.w;
      arow[jj] = a4;
    }
  }

  // ---- pass 2b: gat aggregation (thread = (i, h, par-half of j)) ----
  float acc[32];
#pragma unroll
  for (int q = 0; q < 32; ++q) acc[q] = 0.0f;
  const float mh  = sM[ih];
  const float ish = sIS[ih];
  const float svh = sSrc[ih];

  for (int jt = 0; jt < 16; ++jt) {
    __syncthreads();
    for (int idx = tid; idx < 8192; idx += 256) {
      int jj = idx >> 7, hf = idx & 127;
      sWh[jj][hf >> 5][hf & 31] =
          Wh[((size_t)(b * 1024 + jt * 64 + jj)) * 128 + hf];
    }
    __syncthreads();
    for (int q = 0; q < 32; ++q) {
      const int jj = par + (q << 1);
      const int gj = jt * 64 + jj;
      float e = svh + sDst[gj * 4 + hh];
      e = e > 0.0f ? e : 0.2f * e;
      const float a = __expf((adjrow[gj] ? e : -1e9f) - mh) * ish;
#pragma unroll
      for (int fq = 0; fq < 8; ++fq) {
        const float4 wv = *reinterpret_cast<const float4*>(&sWh[jj][hh][fq * 4]);
        acc[fq * 4 + 0] = fmaf(a, wv.x, acc[fq * 4 + 0]);
        acc[fq * 4 + 1] = fmaf(a, wv.y, acc[fq * 4 + 1]);
        acc[fq * 4 + 2] = fmaf(a, wv.z, acc[fq * 4 + 2]);
        acc[fq * 4 + 3] = fmaf(a, wv.w, acc[fq * 4 + 3]);
      }
    }
  }
  __syncthreads();
  float* sRed = &sWh[0][0][0];   // reuse as 128x32 reduction buffer (16KB)
  if (par == 1) {
#pragma unroll
    for (int q = 0; q < 32; ++q) sRed[ih * 32 + q] = acc[q];
  }
  __syncthreads();
  if (par == 0) {
    float* gout = gat_out + ((size_t)(b * 1024 + itile + il)) * 128 + hh * 32;
#pragma unroll
    for (int q = 0; q < 32; ++q) {
      float v = acc[q] + sRed[ih * 32 + q];
      v = v > 0.0f ? v : (__expf(v) - 1.0f);   // elu
      gout[q] = v;
    }
  }
}

// ---------------------------------------------------------------------------
// MLP chain: res block + fW/LN/tanh + nW1/relu/nW2. Block = 16 rows.
// ---------------------------------------------------------------------------
__global__ __launch_bounds__(256) void mlp_kernel(
    const float* __restrict__ gat,
    const float* __restrict__ rW1, const float* __restrict__ rb1,
    const float* __restrict__ rW2, const float* __restrict__ rb2,
    const float* __restrict__ fW,  const float* __restrict__ fb,
    const float* __restrict__ ln_g, const float* __restrict__ ln_b,
    const float* __restrict__ nW1, const float* __restrict__ nb1,
    const float* __restrict__ nW2, const float* __restrict__ nb2,
    float* __restrict__ out)
{
  __shared__ float sW[128 * 128];
  __shared__ float sZ[16][128];
  __shared__ float sT[16][128];
  __shared__ float sY[16][32];
  __shared__ float sT2[16][32];
  __shared__ float sB1[128], sB2[128];

  const int tid = threadIdx.x;
  const int rowbase = blockIdx.x * 16;

  for (int idx = tid; idx < 16384; idx += 256) sW[idx] = rW1[idx];
  if (tid < 128) { sB1[tid] = rb1[tid]; sB2[tid] = rb2[tid]; }
  for (int idx = tid; idx < 2048; idx += 256)
    sZ[idx >> 7][idx & 127] = gat[(size_t)rowbase * 128 + idx];
  __syncthreads();

  const int c = tid & 127, rblk = tid >> 7;
  // t1 = relu(z @ rW1 + rb1)
  for (int q = 0; q < 8; ++q) {
    const int r = rblk + (q << 1);
    float a = sB1[c];
#pragma unroll 8
    for (int k = 0; k < 128; ++k) a = fmaf(sZ[r][k], sW[k * 128 + c], a);
    sT[r][c] = a > 0.0f ? a : 0.0f;
  }
  __syncthreads();
  for (int idx = tid; idx < 16384; idx += 256) sW[idx] = rW2[idx];
  __syncthreads();
  // res = relu(z + t1 @ rW2 + rb2)
  for (int q = 0; q < 8; ++q) {
    const int r = rblk + (q << 1);
    float a = sB2[c];
#pragma unroll 8
    for (int k = 0; k < 128; ++k) a = fmaf(sT[r][k], sW[k * 128 + c], a);
    a += sZ[r][c];
    sZ[r][c] = a > 0.0f ? a : 0.0f;
  }
  __syncthreads();
  // stage phase-3/4 weights: fW(4096)@0, nW1@4096, nW2@5120, fb@6144,
  // ln_g@6176, ln_b@6208, nb1@6240, nb2@6272
  for (int idx = tid; idx < 4096; idx += 256) sW[idx] = fW[idx];
  for (int idx = tid; idx < 1024; idx += 256) {
    sW[4096 + idx] = nW1[idx];
    sW[5120 + idx] = nW2[idx];
  }
  if (tid < 32) {
    sW[6144 + tid] = fb[tid];
    sW[6176 + tid] = ln_g[tid];
    sW[6208 + tid] = ln_b[tid];
    sW[6240 + tid] = nb1[tid];
    sW[6272 + tid] = nb2[tid];
  }
  __syncthreads();

  const int o = tid & 31, rr2 = tid >> 5;
  // y = res @ fW + fb -> LayerNorm -> tanh
  for (int g = 0; g < 2; ++g) {
    const int r = rr2 + (g << 3);
    float y = sW[6144 + o];
#pragma unroll 8
    for (int k = 0; k < 128; ++k) y = fmaf(sZ[r][k], sW[k * 32 + o], y);
    float mu = y;
#pragma unroll
    for (int m = 16; m >= 1; m >>= 1) mu += __shfl_xor(mu, m, 32);
    mu *= (1.0f / 32.0f);
    const float d = y - mu;
    float var = d * d;
#pragma unroll
    for (int m = 16; m >= 1; m >>= 1) var += __shfl_xor(var, m, 32);
    var *= (1.0f / 32.0f);
    const float yn = d * rsqrtf(var + 1e-5f) * sW[6176 + o] + sW[6208 + o];
    sY[r][o] = tanhf(yn);
  }
  __syncthreads();
  // t2 = relu(y @ nW1 + nb1)
  for (int g = 0; g < 2; ++g) {
    const int r = rr2 + (g << 3);
    float a = sW[6240 + o];
#pragma unroll
    for (int k = 0; k < 32; ++k) a = fmaf(sY[r][k], sW[4096 + k * 32 + o], a);
    sT2[r][o] = a > 0.0f ? a : 0.0f;
  }
  __syncthreads();
  // out = t2 @ nW2 + nb2
  for (int g = 0; g < 2; ++g) {
    const int r = rr2 + (g << 3);
    float a = sW[6272 + o];
#pragma unroll
    for (int k = 0; k < 32; ++k) a = fmaf(sT2[r][k], sW[5120 + k * 32 + o], a);
    out[(size_t)(rowbase + r) * 32 + o] = a;
  }
}

// ---------------------------------------------------------------------------
extern "C" void kernel_launch(void* const* d_in, const int* in_sizes, int n_in,
                              void* d_out, int out_size, void* d_ws, size_t ws_size,
                              hipStream_t stream) {
  const float* seq   = (const float*)d_in[0];
  const int*   adj   = (const int*)d_in[1];
  const float* Wih0  = (const float*)d_in[2];
  const float* Whh0  = (const float*)d_in[3];
  const float* bih0  = (const float*)d_in[4];
  const float* bhh0  = (const float*)d_in[5];
  const float* Wih1  = (const float*)d_in[6];
  const float* Whh1  = (const float*)d_in[7];
  const float* bih1  = (const float*)d_in[8];
  const float* bhh1  = (const float*)d_in[9];
  const float* gatW  = (const float*)d_in[10];
  const float* a_src = (const float*)d_in[11];
  const float* a_dst = (const float*)d_in[12];
  const float* rW1   = (const float*)d_in[13];
  const float* rb1   = (const float*)d_in[14];
  const float* rW2   = (const float*)d_in[15];
  const float* rb2   = (const float*)d_in[16];
  const float* fW    = (const float*)d_in[17];
  const float* fb    = (const float*)d_in[18];
  const float* ln_g  = (const float*)d_in[19];
  const float* ln_b  = (const float*)d_in[20];
  const float* nW1   = (const float*)d_in[21];
  const float* nb1   = (const float*)d_in[22];
  const float* nW2   = (const float*)d_in[23];
  const float* nb2   = (const float*)d_in[24];

  float* out  = (float*)d_out;                  // [BN][32] at offset 0
  float* attn = out + (size_t)BN * OO;          // [B,N,N,4] region (268MB)
  float* h1   = attn;                           // reuse attn region for h1 (134MB, dead before attn written)

  float* ws   = (float*)d_ws;                   // needs ~21.5MB
  float* feat = ws;                             // [BN][64]
  float* Wh   = feat + (size_t)BN * 64;         // [BN][128]
  float* srcv = Wh + (size_t)BN * 128;          // [BN][4]
  float* dstv = srcv + (size_t)BN * 4;          // [BN][4]
  float* gat  = dstv + (size_t)BN * 4;          // [BN][128] (elu applied)

  gru_kernel<<<512, 256, 0, stream>>>(seq, Wih0, Whh0, bih0, bhh0, h1, nullptr);
  gru_kernel<<<512, 256, 0, stream>>>(h1, Wih1, Whh1, bih1, bhh1, nullptr, feat);
  gat_feat_kernel<<<2048, 256, 0, stream>>>(feat, gatW, a_src, a_dst, Wh, srcv, dstv);
  attn_kernel<<<512, 256, 0, stream>>>(Wh, srcv, dstv, adj, attn, gat);
  mlp_kernel<<<1024, 256, 0, stream>>>(gat, rW1, rb1, rW2, rb2, fW, fb,
                                       ln_g, ln_b, nW1, nb1, nW2, nb2, out);
}

// Round 2
// 628.328 us; speedup vs baseline: 2.7451x; 2.7451x over previous
//
#include <hip/hip_runtime.h>

// Problem constants
#define BB 16
#define TT 32
#define NN 1024
#define DD 64
#define HH 64
#define BN 16384          // B*N
#define GH 128
#define RR 128
#define OO 32

typedef __attribute__((ext_vector_type(8))) short short8;
typedef __attribute__((ext_vector_type(4))) float f32x4;

#define MFMA(A, B, C) __builtin_amdgcn_mfma_f32_16x16x32_bf16((A), (B), (C), 0, 0, 0)

__device__ __forceinline__ unsigned short f2bf(float x) {
  unsigned u = __float_as_uint(x);
  unsigned r = (u + 0x7FFFu + ((u >> 16) & 1u)) >> 16;
  return (unsigned short)r;
}
__device__ __forceinline__ float bf2f(unsigned short h) {
  return __uint_as_float(((unsigned)h) << 16);
}
__device__ __forceinline__ float sigmoid_fast(float x) {
  return 1.0f / (1.0f + __expf(-x));
}
__device__ __forceinline__ float tanh_fast(float x) {
  float e = __expf(2.0f * x);
  return 1.0f - 2.0f / (e + 1.0f);
}

// ---------------------------------------------------------------------------
// MFMA GRU layer. Per block: 64 sequences, full T=32 recurrence.
// Per step t: gi = X_t @ WihT, gh = H_t @ WhhT via 16x16x32 bf16 MFMA with
// bf16x3 (hi/lo) splitting for ~fp32 accuracy. Gates computed in-register
// from C/D fragment layout. 512 threads = 8 waves: wave w -> M-tile (w&3,
// seqs 16), j-range (w>>2, 32 cols of the 64 hidden units).
// LDS: W planes [wih_hi, wih_lo, whh_hi, whh_lo] as [192][64] bf16 (B-frag
// friendly: 8 contiguous k per lane), X [64][64] bf16 hi/lo, H double-buffered
// hi/lo. All tiles XOR-swizzled: short_idx = row*64 + (k ^ ((row&7)<<3)).
// ---------------------------------------------------------------------------
__global__ __launch_bounds__(512, 2) void gru_mfma_kernel(
    const float* __restrict__ x,
    const float* __restrict__ Wih, const float* __restrict__ Whh,
    const float* __restrict__ bih, const float* __restrict__ bhh,
    float* __restrict__ h_all, float* __restrict__ h_last)
{
  __shared__ short sW[4][12288];     // [plane][n*64 + swz(k)] : 96 KB
  __shared__ short sX[2][4096];      // [hi/lo][seq*64 + swz(k)] : 16 KB
  __shared__ short sH[2][2][4096];   // [buf][hi/lo][...] : 32 KB

  const int tid = threadIdx.x;
  const int gbase = blockIdx.x * 64;

  // ---- X(0) prefetch to regs (issued first to hide latency) ----
  const int sseq = tid >> 3;             // staging: thread -> (seq, 8-k chunk)
  const int sk0 = (tid & 7) << 3;
  const float* xrow = x + (size_t)(gbase + sseq) * (TT * 64) + sk0;
  float4 p0 = *reinterpret_cast<const float4*>(xrow);
  float4 p1 = *reinterpret_cast<const float4*>(xrow + 4);
  const int sxoff = sseq * 64 + (sk0 ^ ((sseq & 7) << 3));

  // ---- weight staging: fp32 -> bf16 hi/lo, swizzled ----
  for (int idxc = tid; idxc < 1536; idxc += 512) {     // 192 rows x 8 chunks
    const int n = idxc >> 3, k0 = (idxc & 7) << 3;
    const int so = n * 64 + (k0 ^ ((n & 7) << 3));
    float4 a0 = *reinterpret_cast<const float4*>(Wih + n * 64 + k0);
    float4 a1 = *reinterpret_cast<const float4*>(Wih + n * 64 + k0 + 4);
    float4 b0 = *reinterpret_cast<const float4*>(Whh + n * 64 + k0);
    float4 b1 = *reinterpret_cast<const float4*>(Whh + n * 64 + k0 + 4);
    float wa[8] = {a0.x, a0.y, a0.z, a0.w, a1.x, a1.y, a1.z, a1.w};
    float wb[8] = {b0.x, b0.y, b0.z, b0.w, b1.x, b1.y, b1.z, b1.w};
    short8 vah, val, vbh, vbl;
#pragma unroll
    for (int e = 0; e < 8; ++e) {
      unsigned short ha = f2bf(wa[e]);
      vah[e] = (short)ha; val[e] = (short)f2bf(wa[e] - bf2f(ha));
      unsigned short hb = f2bf(wb[e]);
      vbh[e] = (short)hb; vbl[e] = (short)f2bf(wb[e] - bf2f(hb));
    }
    *reinterpret_cast<short8*>(&sW[0][so]) = vah;
    *reinterpret_cast<short8*>(&sW[1][so]) = val;
    *reinterpret_cast<short8*>(&sW[2][so]) = vbh;
    *reinterpret_cast<short8*>(&sW[3][so]) = vbl;
  }
  // zero H buffer 0 (both planes)
  for (int i = tid; i < 4096; i += 512) { sH[0][0][i] = 0; sH[0][1][i] = 0; }

  // ---- per-thread role decode ----
  const int w = tid >> 6, l = tid & 63;
  const int m = w & 3;          // M-tile (16 seqs)
  const int jr = w >> 2;        // j-range: cols [jr*32, jr*32+32)
  const int c = l & 15;         // col within 16-tile / A row within M-tile
  const int rq = l >> 4;        // k-group / C-row-group

  // biases (j0 = jt=0 col, j1 = jt=1 col)
  const int j0 = jr * 32 + c, j1 = j0 + 16;
  float br[2]  = {bih[j0] + bhh[j0], bih[j1] + bhh[j1]};
  float bz[2]  = {bih[64 + j0] + bhh[64 + j0], bih[64 + j1] + bhh[64 + j1]};
  float bni[2] = {bih[128 + j0], bih[128 + j1]};
  float bnh[2] = {bhh[128 + j0], bhh[128 + j1]};

  // A-fragment offsets (X and H planes share layout)
  const int arow = m * 16 + c;
  const int asw = (arow & 7) << 3;
  const int ao0 = arow * 64 + ((rq << 3) ^ asw);
  const int ao1 = arow * 64 + ((32 + (rq << 3)) ^ asw);

  float h[2][4];
#pragma unroll
  for (int jt = 0; jt < 2; ++jt)
#pragma unroll
    for (int q = 0; q < 4; ++q) h[jt][q] = 0.0f;

  for (int t = 0; t < TT; ++t) {
    // prefetch X(t+1) to regs
    float4 n0 = p0, n1 = p1;
    if (t + 1 < TT) {
      n0 = *reinterpret_cast<const float4*>(xrow + (t + 1) * 64);
      n1 = *reinterpret_cast<const float4*>(xrow + (t + 1) * 64 + 4);
    }
    __syncthreads();   // prior compute's reads of sX done
    {
      float xs[8] = {p0.x, p0.y, p0.z, p0.w, p1.x, p1.y, p1.z, p1.w};
      short8 vh, vl;
#pragma unroll
      for (int e = 0; e < 8; ++e) {
        unsigned short hh_ = f2bf(xs[e]);
        vh[e] = (short)hh_; vl[e] = (short)f2bf(xs[e] - bf2f(hh_));
      }
      *reinterpret_cast<short8*>(&sX[0][sxoff]) = vh;
      *reinterpret_cast<short8*>(&sX[1][sxoff]) = vl;
    }
    p0 = n0; p1 = n1;
    __syncthreads();   // X(t) + H(t) visible

    const int cb = t & 1, nb = (t + 1) & 1;
    // A-fragments
    short8 xh[2], xl[2], hh[2], hl[2];
    xh[0] = *reinterpret_cast<const short8*>(&sX[0][ao0]);
    xh[1] = *reinterpret_cast<const short8*>(&sX[0][ao1]);
    xl[0] = *reinterpret_cast<const short8*>(&sX[1][ao0]);
    xl[1] = *reinterpret_cast<const short8*>(&sX[1][ao1]);
    hh[0] = *reinterpret_cast<const short8*>(&sH[cb][0][ao0]);
    hh[1] = *reinterpret_cast<const short8*>(&sH[cb][0][ao1]);
    hl[0] = *reinterpret_cast<const short8*>(&sH[cb][1][ao0]);
    hl[1] = *reinterpret_cast<const short8*>(&sH[cb][1][ao1]);

    f32x4 accr[2], accz[2], accni[2], accnh[2];
#pragma unroll
    for (int jt = 0; jt < 2; ++jt) {
      accr[jt]  = (f32x4){br[jt], br[jt], br[jt], br[jt]};
      accz[jt]  = (f32x4){bz[jt], bz[jt], bz[jt], bz[jt]};
      accni[jt] = (f32x4){bni[jt], bni[jt], bni[jt], bni[jt]};
      accnh[jt] = (f32x4){bnh[jt], bnh[jt], bnh[jt], bnh[jt]};
    }

#pragma unroll
    for (int jt = 0; jt < 2; ++jt) {
      const int nr = jr * 32 + jt * 16 + c;        // r-gate weight row (= out col j)
      const int swz = (nr & 7) << 3;               // (+64/+128 keep nr&7)
#pragma unroll
      for (int ks = 0; ks < 2; ++ks) {
        const int ko = ((ks * 32 + (rq << 3)) ^ swz);
        // r gate: shared acc for gi+gh
        short8 wr_h = *reinterpret_cast<const short8*>(&sW[0][nr * 64 + ko]);
        short8 wr_l = *reinterpret_cast<const short8*>(&sW[1][nr * 64 + ko]);
        short8 vr_h = *reinterpret_cast<const short8*>(&sW[2][nr * 64 + ko]);
        short8 vr_l = *reinterpret_cast<const short8*>(&sW[3][nr * 64 + ko]);
        accr[jt] = MFMA(xh[ks], wr_h, accr[jt]);
        accr[jt] = MFMA(xh[ks], wr_l, accr[jt]);
        accr[jt] = MFMA(xl[ks], wr_h, accr[jt]);
        accr[jt] = MFMA(hh[ks], vr_h, accr[jt]);
        accr[jt] = MFMA(hh[ks], vr_l, accr[jt]);
        accr[jt] = MFMA(hl[ks], vr_h, accr[jt]);
        // z gate
        short8 wz_h = *reinterpret_cast<const short8*>(&sW[0][(64 + nr) * 64 + ko]);
        short8 wz_l = *reinterpret_cast<const short8*>(&sW[1][(64 + nr) * 64 + ko]);
        short8 vz_h = *reinterpret_cast<const short8*>(&sW[2][(64 + nr) * 64 + ko]);
        short8 vz_l = *reinterpret_cast<const short8*>(&sW[3][(64 + nr) * 64 + ko]);
        accz[jt] = MFMA(xh[ks], wz_h, accz[jt]);
        accz[jt] = MFMA(xh[ks], wz_l, accz[jt]);
        accz[jt] = MFMA(xl[ks], wz_h, accz[jt]);
        accz[jt] = MFMA(hh[ks], vz_h, accz[jt]);
        accz[jt] = MFMA(hh[ks], vz_l, accz[jt]);
        accz[jt] = MFMA(hl[ks], vz_h, accz[jt]);
        // n gate: gi and gh separate
        short8 wn_h = *reinterpret_cast<const short8*>(&sW[0][(128 + nr) * 64 + ko]);
        short8 wn_l = *reinterpret_cast<const short8*>(&sW[1][(128 + nr) * 64 + ko]);
        accni[jt] = MFMA(xh[ks], wn_h, accni[jt]);
        accni[jt] = MFMA(xh[ks], wn_l, accni[jt]);
        accni[jt] = MFMA(xl[ks], wn_h, accni[jt]);
        short8 vn_h = *reinterpret_cast<const short8*>(&sW[2][(128 + nr) * 64 + ko]);
        short8 vn_l = *reinterpret_cast<const short8*>(&sW[3][(128 + nr) * 64 + ko]);
        accnh[jt] = MFMA(hh[ks], vn_h, accnh[jt]);
        accnh[jt] = MFMA(hh[ks], vn_l, accnh[jt]);
        accnh[jt] = MFMA(hl[ks], vn_h, accnh[jt]);
      }
    }

    // gates + H(t+1) write + optional h_all store
#pragma unroll
    for (int jt = 0; jt < 2; ++jt) {
      const int jj = jr * 32 + jt * 16 + c;
#pragma unroll
      for (int q = 0; q < 4; ++q) {
        float rg = sigmoid_fast(accr[jt][q]);
        float zg = sigmoid_fast(accz[jt][q]);
        float ng = tanh_fast(fmaf(rg, accnh[jt][q], accni[jt][q]));
        float hv = (1.0f - zg) * ng + zg * h[jt][q];
        h[jt][q] = hv;
        const int seq = m * 16 + (rq << 2) + q;
        const int hoff = seq * 64 + (jj ^ ((seq & 7) << 3));
        unsigned short hh_ = f2bf(hv);
        sH[nb][0][hoff] = (short)hh_;
        sH[nb][1][hoff] = (short)f2bf(hv - bf2f(hh_));
        if (h_all)
          h_all[(size_t)(gbase + seq) * (TT * 64) + t * 64 + jj] = hv;
      }
    }
  }

  if (h_last) {
#pragma unroll
    for (int jt = 0; jt < 2; ++jt) {
      const int jj = jr * 32 + jt * 16 + c;
#pragma unroll
      for (int q = 0; q < 4; ++q) {
        const int seq = m * 16 + (rq << 2) + q;
        h_last[(size_t)(gbase + seq) * 64 + jj] = h[jt][q];
      }
    }
  }
}

// ---------------------------------------------------------------------------
// GAT projection: Wh[i][hf] = sum_k feat[i][k]*gatW[k][hf];
// src/dst[i][h] = sum_f Wh[i][h][f]*a_src/dst[h][f].
// ---------------------------------------------------------------------------
__global__ __launch_bounds__(256) void gat_feat_kernel(
    const float* __restrict__ feat, const float* __restrict__ gatW,
    const float* __restrict__ a_src, const float* __restrict__ a_dst,
    float* __restrict__ Wh, float* __restrict__ srcv, float* __restrict__ dstv)
{
  __shared__ float sGatW[64 * 128];
  __shared__ float sFeat[8][64];
  __shared__ float sAs[128], sAd[128];
  const int tid = threadIdx.x;
  const int rowbase = blockIdx.x * 8;
  for (int idx = tid; idx < 8192; idx += 256) sGatW[idx] = gatW[idx];
  if (tid < 128) { sAs[tid] = a_src[tid]; sAd[tid] = a_dst[tid]; }
  for (int idx = tid; idx < 512; idx += 256)
    sFeat[idx >> 6][idx & 63] = feat[(size_t)rowbase * 64 + idx];
  __syncthreads();

  const int hf = tid & 127, half = tid >> 7;
  const int h = hf >> 5;
  const float as = sAs[hf], ad = sAd[hf];
  for (int rr = half; rr < 8; rr += 2) {
    float acc = 0.0f;
#pragma unroll 8
    for (int k = 0; k < 64; ++k) acc = fmaf(sFeat[rr][k], sGatW[k * 128 + hf], acc);
    const size_t grow = rowbase + rr;
    Wh[grow * 128 + hf] = acc;
    float ps = acc * as, pd = acc * ad;
#pragma unroll
    for (int m = 16; m >= 1; m >>= 1) {
      ps += __shfl_xor(ps, m, 32);
      pd += __shfl_xor(pd, m, 32);
    }
    if ((hf & 31) == 0) {
      srcv[grow * 4 + h] = ps;
      dstv[grow * 4 + h] = pd;
    }
  }
}

// ---------------------------------------------------------------------------
// Attention + gat aggregation.
// ---------------------------------------------------------------------------
__global__ __launch_bounds__(256) void attn_kernel(
    const float* __restrict__ Wh, const float* __restrict__ srcp,
    const float* __restrict__ dstp, const int* __restrict__ adj,
    float* __restrict__ attn_out, float* __restrict__ gat_out)
{
  __shared__ __align__(16) float sDst[1024 * 4];
  __shared__ __align__(16) float sSrc[32 * 4];
  __shared__ __align__(16) float sM[128];
  __shared__ __align__(16) float sIS[128];
  __shared__ float sPart[2][256];
  __shared__ __align__(16) float sWh[64][4][36];

  const int tid = threadIdx.x;
  const int b = blockIdx.x >> 5;
  const int itile = (blockIdx.x & 31) << 5;

  for (int idx = tid; idx < 4096; idx += 256) sDst[idx] = dstp[(size_t)b * 4096 + idx];
  if (tid < 128) sSrc[tid] = srcp[((size_t)b * 1024 + itile) * 4 + tid];
  __syncthreads();

  const int il = tid >> 3, hh = (tid >> 1) & 3, par = tid & 1;
  const int ih = il * 4 + hh;
  const int* adjrow = adj + (size_t)(itile + il) * 1024;
  {
    const float sv = sSrc[ih];
    float m = -1e30f;
    for (int jj = par; jj < 1024; jj += 2) {
      float e = sv + sDst[jj * 4 + hh];
      e = e > 0.0f ? e : 0.2f * e;
      float ev = adjrow[jj] ? e : -1e9f;
      m = fmaxf(m, ev);
    }
    float ssum = 0.0f;
    for (int jj = par; jj < 1024; jj += 2) {
      float e = sv + sDst[jj * 4 + hh];
      e = e > 0.0f ? e : 0.2f * e;
      float ev = adjrow[jj] ? e : -1e9f;
      ssum += __expf(ev - m);
    }
    sPart[par][ih * 2]     = m;
    sPart[par][ih * 2 + 1] = ssum;
  }
  __syncthreads();
  if (par == 0) {
    float m0 = sPart[0][ih * 2], s0 = sPart[0][ih * 2 + 1];
    float m1 = sPart[1][ih * 2], s1 = sPart[1][ih * 2 + 1];
    float m = fmaxf(m0, m1);
    float s = s0 * __expf(m0 - m) + s1 * __expf(m1 - m);
    sM[ih] = m;
    sIS[ih] = 1.0f / s;
  }
  __syncthreads();

  // ---- pass 2a: write attn ----
  {
    const int il_a = tid >> 3, jsub = tid & 7;
    const int* adjA = adj + (size_t)(itile + il_a) * 1024;
    const float4 sv4 = *reinterpret_cast<const float4*>(&sSrc[il_a * 4]);
    const float4 m4  = *reinterpret_cast<const float4*>(&sM[il_a * 4]);
    const float4 is4 = *reinterpret_cast<const float4*>(&sIS[il_a * 4]);
    float4* arow = reinterpret_cast<float4*>(
        attn_out + ((size_t)(b * 1024 + itile + il_a)) * 4096);
    for (int q = 0; q < 128; ++q) {
      const int jj = jsub + (q << 3);
      const int av = adjA[jj];
      const float4 dv = *reinterpret_cast<const float4*>(&sDst[jj * 4]);
      float4 a4;
      float e;
      e = sv4.x + dv.x; e = e > 0.f ? e : 0.2f * e; a4.x = __expf((av ? e : -1e9f) - m4.x) * is4.x;
      e = sv4.y + dv.y; e = e > 0.f ? e : 0.2f * e; a4.y = __expf((av ? e : -1e9f) - m4.y) * is4.y;
      e = sv4.z + dv.z; e = e > 0.f ? e : 0.2f * e; a4.z = __expf((av ? e : -1e9f) - m4.z) * is4.z;
      e = sv4.w + dv.w; e = e > 0.f ? e : 0.2f * e; a4.w = __expf((av ? e : -1e9f) - m4.w) * is4.w;
      arow[jj] = a4;
    }
  }

  // ---- pass 2b: gat aggregation ----
  float acc[32];
#pragma unroll
  for (int q = 0; q < 32; ++q) acc[q] = 0.0f;
  const float mh  = sM[ih];
  const float ish = sIS[ih];
  const float svh = sSrc[ih];

  for (int jt = 0; jt < 16; ++jt) {
    __syncthreads();
    for (int idx = tid; idx < 8192; idx += 256) {
      int jj = idx >> 7, hf = idx & 127;
      sWh[jj][hf >> 5][hf & 31] =
          Wh[((size_t)(b * 1024 + jt * 64 + jj)) * 128 + hf];
    }
    __syncthreads();
    for (int q = 0; q < 32; ++q) {
      const int jj = par + (q << 1);
      const int gj = jt * 64 + jj;
      float e = svh + sDst[gj * 4 + hh];
      e = e > 0.0f ? e : 0.2f * e;
      const float a = __expf((adjrow[gj] ? e : -1e9f) - mh) * ish;
#pragma unroll
      for (int fq = 0; fq < 8; ++fq) {
        const float4 wv = *reinterpret_cast<const float4*>(&sWh[jj][hh][fq * 4]);
        acc[fq * 4 + 0] = fmaf(a, wv.x, acc[fq * 4 + 0]);
        acc[fq * 4 + 1] = fmaf(a, wv.y, acc[fq * 4 + 1]);
        acc[fq * 4 + 2] = fmaf(a, wv.z, acc[fq * 4 + 2]);
        acc[fq * 4 + 3] = fmaf(a, wv.w, acc[fq * 4 + 3]);
      }
    }
  }
  __syncthreads();
  float* sRed = &sWh[0][0][0];
  if (par == 1) {
#pragma unroll
    for (int q = 0; q < 32; ++q) sRed[ih * 32 + q] = acc[q];
  }
  __syncthreads();
  if (par == 0) {
    float* gout = gat_out + ((size_t)(b * 1024 + itile + il)) * 128 + hh * 32;
#pragma unroll
    for (int q = 0; q < 32; ++q) {
      float v = acc[q] + sRed[ih * 32 + q];
      v = v > 0.0f ? v : (__expf(v) - 1.0f);
      gout[q] = v;
    }
  }
}

// ---------------------------------------------------------------------------
// MLP chain: res block + fW/LN/tanh + nW1/relu/nW2.
// ---------------------------------------------------------------------------
__global__ __launch_bounds__(256) void mlp_kernel(
    const float* __restrict__ gat,
    const float* __restrict__ rW1, const float* __restrict__ rb1,
    const float* __restrict__ rW2, const float* __restrict__ rb2,
    const float* __restrict__ fW,  const float* __restrict__ fb,
    const float* __restrict__ ln_g, const float* __restrict__ ln_b,
    const float* __restrict__ nW1, const float* __restrict__ nb1,
    const float* __restrict__ nW2, const float* __restrict__ nb2,
    float* __restrict__ out)
{
  __shared__ float sW[128 * 128];
  __shared__ float sZ[16][128];
  __shared__ float sT[16][128];
  __shared__ float sY[16][32];
  __shared__ float sT2[16][32];
  __shared__ float sB1[128], sB2[128];

  const int tid = threadIdx.x;
  const int rowbase = blockIdx.x * 16;

  for (int idx = tid; idx < 16384; idx += 256) sW[idx] = rW1[idx];
  if (tid < 128) { sB1[tid] = rb1[tid]; sB2[tid] = rb2[tid]; }
  for (int idx = tid; idx < 2048; idx += 256)
    sZ[idx >> 7][idx & 127] = gat[(size_t)rowbase * 128 + idx];
  __syncthreads();

  const int c = tid & 127, rblk = tid >> 7;
  for (int q = 0; q < 8; ++q) {
    const int r = rblk + (q << 1);
    float a = sB1[c];
#pragma unroll 8
    for (int k = 0; k < 128; ++k) a = fmaf(sZ[r][k], sW[k * 128 + c], a);
    sT[r][c] = a > 0.0f ? a : 0.0f;
  }
  __syncthreads();
  for (int idx = tid; idx < 16384; idx += 256) sW[idx] = rW2[idx];
  __syncthreads();
  for (int q = 0; q < 8; ++q) {
    const int r = rblk + (q << 1);
    float a = sB2[c];
#pragma unroll 8
    for (int k = 0; k < 128; ++k) a = fmaf(sT[r][k], sW[k * 128 + c], a);
    a += sZ[r][c];
    sZ[r][c] = a > 0.0f ? a : 0.0f;
  }
  __syncthreads();
  for (int idx = tid; idx < 4096; idx += 256) sW[idx] = fW[idx];
  for (int idx = tid; idx < 1024; idx += 256) {
    sW[4096 + idx] = nW1[idx];
    sW[5120 + idx] = nW2[idx];
  }
  if (tid < 32) {
    sW[6144 + tid] = fb[tid];
    sW[6176 + tid] = ln_g[tid];
    sW[6208 + tid] = ln_b[tid];
    sW[6240 + tid] = nb1[tid];
    sW[6272 + tid] = nb2[tid];
  }
  __syncthreads();

  const int o = tid & 31, rr2 = tid >> 5;
  for (int g = 0; g < 2; ++g) {
    const int r = rr2 + (g << 3);
    float y = sW[6144 + o];
#pragma unroll 8
    for (int k = 0; k < 128; ++k) y = fmaf(sZ[r][k], sW[k * 32 + o], y);
    float mu = y;
#pragma unroll
    for (int m = 16; m >= 1; m >>= 1) mu += __shfl_xor(mu, m, 32);
    mu *= (1.0f / 32.0f);
    const float d = y - mu;
    float var = d * d;
#pragma unroll
    for (int m = 16; m >= 1; m >>= 1) var += __shfl_xor(var, m, 32);
    var *= (1.0f / 32.0f);
    const float yn = d * rsqrtf(var + 1e-5f) * sW[6176 + o] + sW[6208 + o];
    sY[r][o] = tanhf(yn);
  }
  __syncthreads();
  for (int g = 0; g < 2; ++g) {
    const int r = rr2 + (g << 3);
    float a = sW[6240 + o];
#pragma unroll
    for (int k = 0; k < 32; ++k) a = fmaf(sY[r][k], sW[4096 + k * 32 + o], a);
    sT2[r][o] = a > 0.0f ? a : 0.0f;
  }
  __syncthreads();
  for (int g = 0; g < 2; ++g) {
    const int r = rr2 + (g << 3);
    float a = sW[6272 + o];
#pragma unroll
    for (int k = 0; k < 32; ++k) a = fmaf(sT2[r][k], sW[5120 + k * 32 + o], a);
    out[(size_t)(rowbase + r) * 32 + o] = a;
  }
}

// ---------------------------------------------------------------------------
extern "C" void kernel_launch(void* const* d_in, const int* in_sizes, int n_in,
                              void* d_out, int out_size, void* d_ws, size_t ws_size,
                              hipStream_t stream) {
  const float* seq   = (const float*)d_in[0];
  const int*   adj   = (const int*)d_in[1];
  const float* Wih0  = (const float*)d_in[2];
  const float* Whh0  = (const float*)d_in[3];
  const float* bih0  = (const float*)d_in[4];
  const float* bhh0  = (const float*)d_in[5];
  const float* Wih1  = (const float*)d_in[6];
  const float* Whh1  = (const float*)d_in[7];
  const float* bih1  = (const float*)d_in[8];
  const float* bhh1  = (const float*)d_in[9];
  const float* gatW  = (const float*)d_in[10];
  const float* a_src = (const float*)d_in[11];
  const float* a_dst = (const float*)d_in[12];
  const float* rW1   = (const float*)d_in[13];
  const float* rb1   = (const float*)d_in[14];
  const float* rW2   = (const float*)d_in[15];
  const float* rb2   = (const float*)d_in[16];
  const float* fW    = (const float*)d_in[17];
  const float* fb    = (const float*)d_in[18];
  const float* ln_g  = (const float*)d_in[19];
  const float* ln_b  = (const float*)d_in[20];
  const float* nW1   = (const float*)d_in[21];
  const float* nb1   = (const float*)d_in[22];
  const float* nW2   = (const float*)d_in[23];
  const float* nb2   = (const float*)d_in[24];

  float* out  = (float*)d_out;                  // [BN][32] at offset 0
  float* attn = out + (size_t)BN * OO;          // [B,N,N,4] region (268MB)
  float* h1   = attn;                           // reuse attn region for h1

  float* ws   = (float*)d_ws;
  float* feat = ws;                             // [BN][64]
  float* Wh   = feat + (size_t)BN * 64;         // [BN][128]
  float* srcv = Wh + (size_t)BN * 128;          // [BN][4]
  float* dstv = srcv + (size_t)BN * 4;          // [BN][4]
  float* gat  = dstv + (size_t)BN * 4;          // [BN][128]

  gru_mfma_kernel<<<256, 512, 0, stream>>>(seq, Wih0, Whh0, bih0, bhh0, h1, nullptr);
  gru_mfma_kernel<<<256, 512, 0, stream>>>(h1, Wih1, Whh1, bih1, bhh1, nullptr, feat);
  gat_feat_kernel<<<2048, 256, 0, stream>>>(feat, gatW, a_src, a_dst, Wh, srcv, dstv);
  attn_kernel<<<512, 256, 0, stream>>>(Wh, srcv, dstv, adj, attn, gat);
  mlp_kernel<<<1024, 256, 0, stream>>>(gat, rW1, rb1, rW2, rb2, fW, fb,
                                       ln_g, ln_b, nW1, nb1, nW2, nb2, out);
}

// Round 4
// 465.345 us; speedup vs baseline: 3.7065x; 1.3502x over previous
//
#include <hip/hip_runtime.h>

// Problem constants
#define BB 16
#define TT 32
#define NN 1024
#define DD 64
#define HH 64
#define BN 16384          // B*N
#define GH 128
#define RR 128
#define OO 32

typedef __attribute__((ext_vector_type(8))) short short8;
typedef __attribute__((ext_vector_type(4))) float f32x4;

#define MFMA(A, B, C) __builtin_amdgcn_mfma_f32_16x16x32_bf16((A), (B), (C), 0, 0, 0)

__device__ __forceinline__ unsigned short f2bf(float x) {
  unsigned u = __float_as_uint(x);
  unsigned r = (u + 0x7FFFu + ((u >> 16) & 1u)) >> 16;
  return (unsigned short)r;
}
__device__ __forceinline__ float bf2f(unsigned short h) {
  return __uint_as_float(((unsigned)h) << 16);
}
__device__ __forceinline__ float sigmoid_fast(float x) {
  return 1.0f / (1.0f + __expf(-x));
}
__device__ __forceinline__ float tanh_fast(float x) {
  float e = __expf(2.0f * x);
  return 1.0f - 2.0f / (e + 1.0f);
}
__device__ __forceinline__ float leaky02(float x) {
  return fmaxf(x, 0.2f * x);
}

// ---------------------------------------------------------------------------
// MFMA GRU layer (unchanged from R1).
// ---------------------------------------------------------------------------
__global__ __launch_bounds__(512, 2) void gru_mfma_kernel(
    const float* __restrict__ x,
    const float* __restrict__ Wih, const float* __restrict__ Whh,
    const float* __restrict__ bih, const float* __restrict__ bhh,
    float* __restrict__ h_all, float* __restrict__ h_last)
{
  __shared__ short sW[4][12288];     // [plane][n*64 + swz(k)] : 96 KB
  __shared__ short sX[2][4096];      // [hi/lo][seq*64 + swz(k)] : 16 KB
  __shared__ short sH[2][2][4096];   // [buf][hi/lo][...] : 32 KB

  const int tid = threadIdx.x;
  const int gbase = blockIdx.x * 64;

  const int sseq = tid >> 3;
  const int sk0 = (tid & 7) << 3;
  const float* xrow = x + (size_t)(gbase + sseq) * (TT * 64) + sk0;
  float4 p0 = *reinterpret_cast<const float4*>(xrow);
  float4 p1 = *reinterpret_cast<const float4*>(xrow + 4);
  const int sxoff = sseq * 64 + (sk0 ^ ((sseq & 7) << 3));

  for (int idxc = tid; idxc < 1536; idxc += 512) {
    const int n = idxc >> 3, k0 = (idxc & 7) << 3;
    const int so = n * 64 + (k0 ^ ((n & 7) << 3));
    float4 a0 = *reinterpret_cast<const float4*>(Wih + n * 64 + k0);
    float4 a1 = *reinterpret_cast<const float4*>(Wih + n * 64 + k0 + 4);
    float4 b0 = *reinterpret_cast<const float4*>(Whh + n * 64 + k0);
    float4 b1 = *reinterpret_cast<const float4*>(Whh + n * 64 + k0 + 4);
    float wa[8] = {a0.x, a0.y, a0.z, a0.w, a1.x, a1.y, a1.z, a1.w};
    float wb[8] = {b0.x, b0.y, b0.z, b0.w, b1.x, b1.y, b1.z, b1.w};
    short8 vah, val, vbh, vbl;
#pragma unroll
    for (int e = 0; e < 8; ++e) {
      unsigned short ha = f2bf(wa[e]);
      vah[e] = (short)ha; val[e] = (short)f2bf(wa[e] - bf2f(ha));
      unsigned short hb = f2bf(wb[e]);
      vbh[e] = (short)hb; vbl[e] = (short)f2bf(wb[e] - bf2f(hb));
    }
    *reinterpret_cast<short8*>(&sW[0][so]) = vah;
    *reinterpret_cast<short8*>(&sW[1][so]) = val;
    *reinterpret_cast<short8*>(&sW[2][so]) = vbh;
    *reinterpret_cast<short8*>(&sW[3][so]) = vbl;
  }
  for (int i = tid; i < 4096; i += 512) { sH[0][0][i] = 0; sH[0][1][i] = 0; }

  const int w = tid >> 6, l = tid & 63;
  const int m = w & 3;
  const int jr = w >> 2;
  const int c = l & 15;
  const int rq = l >> 4;

  const int j0 = jr * 32 + c, j1 = j0 + 16;
  float br[2]  = {bih[j0] + bhh[j0], bih[j1] + bhh[j1]};
  float bz[2]  = {bih[64 + j0] + bhh[64 + j0], bih[64 + j1] + bhh[64 + j1]};
  float bni[2] = {bih[128 + j0], bih[128 + j1]};
  float bnh[2] = {bhh[128 + j0], bhh[128 + j1]};

  const int arow = m * 16 + c;
  const int asw = (arow & 7) << 3;
  const int ao0 = arow * 64 + ((rq << 3) ^ asw);
  const int ao1 = arow * 64 + ((32 + (rq << 3)) ^ asw);

  float h[2][4];
#pragma unroll
  for (int jt = 0; jt < 2; ++jt)
#pragma unroll
    for (int q = 0; q < 4; ++q) h[jt][q] = 0.0f;

  for (int t = 0; t < TT; ++t) {
    float4 n0 = p0, n1 = p1;
    if (t + 1 < TT) {
      n0 = *reinterpret_cast<const float4*>(xrow + (t + 1) * 64);
      n1 = *reinterpret_cast<const float4*>(xrow + (t + 1) * 64 + 4);
    }
    __syncthreads();
    {
      float xs[8] = {p0.x, p0.y, p0.z, p0.w, p1.x, p1.y, p1.z, p1.w};
      short8 vh, vl;
#pragma unroll
      for (int e = 0; e < 8; ++e) {
        unsigned short hh_ = f2bf(xs[e]);
        vh[e] = (short)hh_; vl[e] = (short)f2bf(xs[e] - bf2f(hh_));
      }
      *reinterpret_cast<short8*>(&sX[0][sxoff]) = vh;
      *reinterpret_cast<short8*>(&sX[1][sxoff]) = vl;
    }
    p0 = n0; p1 = n1;
    __syncthreads();

    const int cb = t & 1, nb = (t + 1) & 1;
    short8 xh[2], xl[2], hh[2], hl[2];
    xh[0] = *reinterpret_cast<const short8*>(&sX[0][ao0]);
    xh[1] = *reinterpret_cast<const short8*>(&sX[0][ao1]);
    xl[0] = *reinterpret_cast<const short8*>(&sX[1][ao0]);
    xl[1] = *reinterpret_cast<const short8*>(&sX[1][ao1]);
    hh[0] = *reinterpret_cast<const short8*>(&sH[cb][0][ao0]);
    hh[1] = *reinterpret_cast<const short8*>(&sH[cb][0][ao1]);
    hl[0] = *reinterpret_cast<const short8*>(&sH[cb][1][ao0]);
    hl[1] = *reinterpret_cast<const short8*>(&sH[cb][1][ao1]);

    f32x4 accr[2], accz[2], accni[2], accnh[2];
#pragma unroll
    for (int jt = 0; jt < 2; ++jt) {
      accr[jt]  = (f32x4){br[jt], br[jt], br[jt], br[jt]};
      accz[jt]  = (f32x4){bz[jt], bz[jt], bz[jt], bz[jt]};
      accni[jt] = (f32x4){bni[jt], bni[jt], bni[jt], bni[jt]};
      accnh[jt] = (f32x4){bnh[jt], bnh[jt], bnh[jt], bnh[jt]};
    }

#pragma unroll
    for (int jt = 0; jt < 2; ++jt) {
      const int nr = jr * 32 + jt * 16 + c;
      const int swz = (nr & 7) << 3;
#pragma unroll
      for (int ks = 0; ks < 2; ++ks) {
        const int ko = ((ks * 32 + (rq << 3)) ^ swz);
        short8 wr_h = *reinterpret_cast<const short8*>(&sW[0][nr * 64 + ko]);
        short8 wr_l = *reinterpret_cast<const short8*>(&sW[1][nr * 64 + ko]);
        short8 vr_h = *reinterpret_cast<const short8*>(&sW[2][nr * 64 + ko]);
        short8 vr_l = *reinterpret_cast<const short8*>(&sW[3][nr * 64 + ko]);
        accr[jt] = MFMA(xh[ks], wr_h, accr[jt]);
        accr[jt] = MFMA(xh[ks], wr_l, accr[jt]);
        accr[jt] = MFMA(xl[ks], wr_h, accr[jt]);
        accr[jt] = MFMA(hh[ks], vr_h, accr[jt]);
        accr[jt] = MFMA(hh[ks], vr_l, accr[jt]);
        accr[jt] = MFMA(hl[ks], vr_h, accr[jt]);
        short8 wz_h = *reinterpret_cast<const short8*>(&sW[0][(64 + nr) * 64 + ko]);
        short8 wz_l = *reinterpret_cast<const short8*>(&sW[1][(64 + nr) * 64 + ko]);
        short8 vz_h = *reinterpret_cast<const short8*>(&sW[2][(64 + nr) * 64 + ko]);
        short8 vz_l = *reinterpret_cast<const short8*>(&sW[3][(64 + nr) * 64 + ko]);
        accz[jt] = MFMA(xh[ks], wz_h, accz[jt]);
        accz[jt] = MFMA(xh[ks], wz_l, accz[jt]);
        accz[jt] = MFMA(xl[ks], wz_h, accz[jt]);
        accz[jt] = MFMA(hh[ks], vz_h, accz[jt]);
        accz[jt] = MFMA(hh[ks], vz_l, accz[jt]);
        accz[jt] = MFMA(hl[ks], vz_h, accz[jt]);
        short8 wn_h = *reinterpret_cast<const short8*>(&sW[0][(128 + nr) * 64 + ko]);
        short8 wn_l = *reinterpret_cast<const short8*>(&sW[1][(128 + nr) * 64 + ko]);
        accni[jt] = MFMA(xh[ks], wn_h, accni[jt]);
        accni[jt] = MFMA(xh[ks], wn_l, accni[jt]);
        accni[jt] = MFMA(xl[ks], wn_h, accni[jt]);
        short8 vn_h = *reinterpret_cast<const short8*>(&sW[2][(128 + nr) * 64 + ko]);
        short8 vn_l = *reinterpret_cast<const short8*>(&sW[3][(128 + nr) * 64 + ko]);
        accnh[jt] = MFMA(hh[ks], vn_h, accnh[jt]);
        accnh[jt] = MFMA(hh[ks], vn_l, accnh[jt]);
        accnh[jt] = MFMA(hl[ks], vn_h, accnh[jt]);
      }
    }

#pragma unroll
    for (int jt = 0; jt < 2; ++jt) {
      const int jj = jr * 32 + jt * 16 + c;
#pragma unroll
      for (int q = 0; q < 4; ++q) {
        float rg = sigmoid_fast(accr[jt][q]);
        float zg = sigmoid_fast(accz[jt][q]);
        float ng = tanh_fast(fmaf(rg, accnh[jt][q], accni[jt][q]));
        float hv = (1.0f - zg) * ng + zg * h[jt][q];
        h[jt][q] = hv;
        const int seq = m * 16 + (rq << 2) + q;
        const int hoff = seq * 64 + (jj ^ ((seq & 7) << 3));
        unsigned short hh_ = f2bf(hv);
        sH[nb][0][hoff] = (short)hh_;
        sH[nb][1][hoff] = (short)f2bf(hv - bf2f(hh_));
        if (h_all)
          h_all[(size_t)(gbase + seq) * (TT * 64) + t * 64 + jj] = hv;
      }
    }
  }

  if (h_last) {
#pragma unroll
    for (int jt = 0; jt < 2; ++jt) {
      const int jj = jr * 32 + jt * 16 + c;
#pragma unroll
      for (int q = 0; q < 4; ++q) {
        const int seq = m * 16 + (rq << 2) + q;
        h_last[(size_t)(gbase + seq) * 64 + jj] = h[jt][q];
      }
    }
  }
}

// ---------------------------------------------------------------------------
// GAT projection (unchanged).
// ---------------------------------------------------------------------------
__global__ __launch_bounds__(256) void gat_feat_kernel(
    const float* __restrict__ feat, const float* __restrict__ gatW,
    const float* __restrict__ a_src, const float* __restrict__ a_dst,
    float* __restrict__ Wh, float* __restrict__ srcv, float* __restrict__ dstv)
{
  __shared__ float sGatW[64 * 128];
  __shared__ float sFeat[8][64];
  __shared__ float sAs[128], sAd[128];
  const int tid = threadIdx.x;
  const int rowbase = blockIdx.x * 8;
  for (int idx = tid; idx < 8192; idx += 256) sGatW[idx] = gatW[idx];
  if (tid < 128) { sAs[tid] = a_src[tid]; sAd[tid] = a_dst[tid]; }
  for (int idx = tid; idx < 512; idx += 256)
    sFeat[idx >> 6][idx & 63] = feat[(size_t)rowbase * 64 + idx];
  __syncthreads();

  const int hf = tid & 127, half = tid >> 7;
  const int h = hf >> 5;
  const float as = sAs[hf], ad = sAd[hf];
  for (int rr = half; rr < 8; rr += 2) {
    float acc = 0.0f;
#pragma unroll 8
    for (int k = 0; k < 64; ++k) acc = fmaf(sFeat[rr][k], sGatW[k * 128 + hf], acc);
    const size_t grow = rowbase + rr;
    Wh[grow * 128 + hf] = acc;
    float ps = acc * as, pd = acc * ad;
#pragma unroll
    for (int m = 16; m >= 1; m >>= 1) {
      ps += __shfl_xor(ps, m, 32);
      pd += __shfl_xor(pd, m, 32);
    }
    if ((hf & 31) == 0) {
      srcv[grow * 4 + h] = ps;
      dstv[grow * 4 + h] = pd;
    }
  }
}

// ---------------------------------------------------------------------------
// Attention + gat aggregation, v2.
// Block = (b, 32-row i-tile), 256 thr. No max pass (logits bounded, m=0).
// adj staged as LDS bitmask. Pass1: row sums. Pass2 (32 j-tiles): compute
// a once, write attn (nontemporal f32x4), stage a & Wh as bf16 hi/lo in LDS,
// MFMA per-head [32x32]@[32x32] aggregation with 3-way hi/lo split.
// LDS ~61KB -> 2 blocks/CU.
// ---------------------------------------------------------------------------
__global__ __launch_bounds__(256) void attn_kernel(
    const float* __restrict__ Wh, const float* __restrict__ srcp,
    const float* __restrict__ dstp, const int* __restrict__ adj,
    float* __restrict__ attn_out, float* __restrict__ gat_out)
{
  __shared__ __align__(16) float sDst[4096];          // 16 KB
  __shared__ __align__(16) float sSrc[128];
  __shared__ __align__(16) float sIS[128];            // 1/sum (or -1 sentinel)
  __shared__ unsigned int sAdjW[32][32];              // 4 KB bitmask
  __shared__ __align__(16) unsigned short sPhi[4][32][40];  // 10 KB
  __shared__ __align__(16) unsigned short sPlo[4][32][40];  // 10 KB
  __shared__ __align__(16) unsigned short sBhi[4][32][40];  // 10 KB
  __shared__ __align__(16) unsigned short sBlo[4][32][40];  // 10 KB

  const int tid = threadIdx.x;
  const int bid = blockIdx.x;
  const int swzb = ((bid & 7) << 6) | (bid >> 3);     // XCD-cluster swizzle
  const int b = swzb >> 5;
  const int itile = (swzb & 31) << 5;

  // ---- stage dst, src ----
  for (int idx = tid; idx < 4096; idx += 256) sDst[idx] = dstp[(size_t)b * 4096 + idx];
  if (tid < 128) sSrc[tid] = srcp[((size_t)b * 1024 + itile) * 4 + tid];

  // ---- build adj bitmask: thread -> (row=tid>>3, 4 words) ----
  {
    const int row = tid >> 3;
    const int w0 = (tid & 7) << 2;
    const int* arow_g = adj + (size_t)(itile + row) * 1024 + (w0 << 5);
#pragma unroll
    for (int wq = 0; wq < 4; ++wq) {
      unsigned int word = 0;
#pragma unroll
      for (int c4 = 0; c4 < 8; ++c4) {
        int4 v = *reinterpret_cast<const int4*>(arow_g + (wq << 5) + (c4 << 2));
        word |= (unsigned)((v.x != 0) ? 1 : 0) << (c4 * 4 + 0);
        word |= (unsigned)((v.y != 0) ? 1 : 0) << (c4 * 4 + 1);
        word |= (unsigned)((v.z != 0) ? 1 : 0) << (c4 * 4 + 2);
        word |= (unsigned)((v.w != 0) ? 1 : 0) << (c4 * 4 + 3);
      }
      sAdjW[row][w0 + wq] = word;
    }
  }
  __syncthreads();

  // ---- pass 1: s[i][h] = sum_j mask*exp(leaky(src+dst)), m=0 ----
  {
    const int i = tid >> 3;          // 0..31
    const int par = tid & 7;         // 8-way j split
    const float4 sv = *reinterpret_cast<const float4*>(&sSrc[i * 4]);
    f32x4 acc = (f32x4){0.f, 0.f, 0.f, 0.f};
    const unsigned int bit0 = 1u << par;
    for (int kw = 0; kw < 32; ++kw) {
      const unsigned int word = sAdjW[i][kw];
#pragma unroll
      for (int e = 0; e < 4; ++e) {
        const int gj = (kw << 5) + (e << 3) + par;
        const float4 dv = *reinterpret_cast<const float4*>(&sDst[gj * 4]);
        const float mf = (word & (bit0 << (e << 3))) ? 1.0f : 0.0f;
        acc[0] = fmaf(mf, __expf(leaky02(sv.x + dv.x)), acc[0]);
        acc[1] = fmaf(mf, __expf(leaky02(sv.y + dv.y)), acc[1]);
        acc[2] = fmaf(mf, __expf(leaky02(sv.z + dv.z)), acc[2]);
        acc[3] = fmaf(mf, __expf(leaky02(sv.w + dv.w)), acc[3]);
      }
    }
#pragma unroll
    for (int m = 1; m < 8; m <<= 1) {
#pragma unroll
      for (int q = 0; q < 4; ++q) acc[q] += __shfl_xor(acc[q], m, 64);
    }
    if (par == 0) {
      float4 isv;
      isv.x = acc[0] > 0.f ? 1.0f / acc[0] : -1.0f;
      isv.y = acc[1] > 0.f ? 1.0f / acc[1] : -1.0f;
      isv.z = acc[2] > 0.f ? 1.0f / acc[2] : -1.0f;
      isv.w = acc[3] > 0.f ? 1.0f / acc[3] : -1.0f;
      *reinterpret_cast<float4*>(&sIS[i * 4]) = isv;
    }
  }
  __syncthreads();

  // ---- pass 2: 32 j-tiles of 32 ----
  const int il = tid >> 3;          // 0..31 (i row)
  const int jsub = tid & 7;
  const int wv = tid >> 6;          // wave id = head for MFMA phase
  const int l = tid & 63;
  const int jjB = tid & 31;         // B-staging: Wh row within tile
  const int fcB = tid >> 5;         // B-staging: 16-hf chunk

  const float4 sv4 = *reinterpret_cast<const float4*>(&sSrc[il * 4]);
  const float4 is4 = *reinterpret_cast<const float4*>(&sIS[il * 4]);
  f32x4* arow_out = reinterpret_cast<f32x4*>(
      attn_out + ((size_t)(b * 1024 + itile + il)) * 4096);

  f32x4 accg[2][2];
#pragma unroll
  for (int m = 0; m < 2; ++m)
#pragma unroll
    for (int n = 0; n < 2; ++n) accg[m][n] = (f32x4){0.f, 0.f, 0.f, 0.f};

  // A/B fragment LDS offsets (element index into [32][40] plane)
  const int frow = l & 15, fchunk = l >> 4;
  const int wplane = wv * (32 * 40);

  for (int jt = 0; jt < 32; ++jt) {
    const int j0 = jt << 5;
    // -- compute & write phase --
    {
      const unsigned int word = sAdjW[il][jt];
#pragma unroll
      for (int q = 0; q < 4; ++q) {
        const int j = jsub + (q << 3);
        const int gj = j0 + j;
        const float4 dv = *reinterpret_cast<const float4*>(&sDst[gj * 4]);
        const float mf = (word & (1u << j)) ? 1.0f : 0.0f;
        f32x4 a4;
        float ex;
        ex = mf * __expf(leaky02(sv4.x + dv.x)); a4[0] = ex * is4.x; if (is4.x < 0.f) a4[0] = 9.765625e-4f;
        ex = mf * __expf(leaky02(sv4.y + dv.y)); a4[1] = ex * is4.y; if (is4.y < 0.f) a4[1] = 9.765625e-4f;
        ex = mf * __expf(leaky02(sv4.z + dv.z)); a4[2] = ex * is4.z; if (is4.z < 0.f) a4[2] = 9.765625e-4f;
        ex = mf * __expf(leaky02(sv4.w + dv.w)); a4[3] = ex * is4.w; if (is4.w < 0.f) a4[3] = 9.765625e-4f;
        __builtin_nontemporal_store(a4, &arow_out[gj]);
        float av[4] = {a4[0], a4[1], a4[2], a4[3]};
#pragma unroll
        for (int h = 0; h < 4; ++h) {
          unsigned short hi = f2bf(av[h]);
          sPhi[h][il][j] = hi;
          sPlo[h][il][j] = f2bf(av[h] - bf2f(hi));
        }
      }
      // B staging: Wh[j0+jjB][fcB*16..+16] -> sB[h][f][jjB]
      const float* wrow = Wh + ((size_t)(b * 1024 + j0 + jjB)) * 128 + (fcB << 4);
#pragma unroll
      for (int c4 = 0; c4 < 4; ++c4) {
        float4 v = *reinterpret_cast<const float4*>(wrow + (c4 << 2));
        float vv[4] = {v.x, v.y, v.z, v.w};
#pragma unroll
        for (int e = 0; e < 4; ++e) {
          const int hf = (fcB << 4) + (c4 << 2) + e;
          const int h = hf >> 5, f = hf & 31;
          unsigned short hi = f2bf(vv[e]);
          sBhi[h][f][jjB] = hi;
          sBlo[h][f][jjB] = f2bf(vv[e] - bf2f(hi));
        }
      }
    }
    __syncthreads();
    // -- MFMA phase: wave wv handles head wv --
    {
      short8 ahi[2], alo[2], bhi[2], blo[2];
#pragma unroll
      for (int m = 0; m < 2; ++m) {
        const int ro = wplane + (m * 16 + frow) * 40 + fchunk * 8;
        ahi[m] = *reinterpret_cast<const short8*>(&sPhi[0][0][0] + ro);
        alo[m] = *reinterpret_cast<const short8*>(&sPlo[0][0][0] + ro);
      }
#pragma unroll
      for (int n = 0; n < 2; ++n) {
        const int ro = wplane + (n * 16 + frow) * 40 + fchunk * 8;
        bhi[n] = *reinterpret_cast<const short8*>(&sBhi[0][0][0] + ro);
        blo[n] = *reinterpret_cast<const short8*>(&sBlo[0][0][0] + ro);
      }
#pragma unroll
      for (int m = 0; m < 2; ++m)
#pragma unroll
        for (int n = 0; n < 2; ++n) {
          accg[m][n] = MFMA(ahi[m], bhi[n], accg[m][n]);
          accg[m][n] = MFMA(ahi[m], blo[n], accg[m][n]);
          accg[m][n] = MFMA(alo[m], bhi[n], accg[m][n]);
        }
    }
    __syncthreads();
  }

  // ---- epilogue: elu + store gat ----
#pragma unroll
  for (int m = 0; m < 2; ++m)
#pragma unroll
    for (int n = 0; n < 2; ++n)
#pragma unroll
      for (int q = 0; q < 4; ++q) {
        const int i = m * 16 + (l >> 4) * 4 + q;
        const int f = n * 16 + (l & 15);
        float v = accg[m][n][q];
        v = v > 0.0f ? v : (__expf(v) - 1.0f);
        gat_out[((size_t)(b * 1024 + itile + i)) * 128 + wv * 32 + f] = v;
      }
}

// ---------------------------------------------------------------------------
// MLP chain (unchanged).
// ---------------------------------------------------------------------------
__global__ __launch_bounds__(256) void mlp_kernel(
    const float* __restrict__ gat,
    const float* __restrict__ rW1, const float* __restrict__ rb1,
    const float* __restrict__ rW2, const float* __restrict__ rb2,
    const float* __restrict__ fW,  const float* __restrict__ fb,
    const float* __restrict__ ln_g, const float* __restrict__ ln_b,
    const float* __restrict__ nW1, const float* __restrict__ nb1,
    const float* __restrict__ nW2, const float* __restrict__ nb2,
    float* __restrict__ out)
{
  __shared__ float sW[128 * 128];
  __shared__ float sZ[16][128];
  __shared__ float sT[16][128];
  __shared__ float sY[16][32];
  __shared__ float sT2[16][32];
  __shared__ float sB1[128], sB2[128];

  const int tid = threadIdx.x;
  const int rowbase = blockIdx.x * 16;

  for (int idx = tid; idx < 16384; idx += 256) sW[idx] = rW1[idx];
  if (tid < 128) { sB1[tid] = rb1[tid]; sB2[tid] = rb2[tid]; }
  for (int idx = tid; idx < 2048; idx += 256)
    sZ[idx >> 7][idx & 127] = gat[(size_t)rowbase * 128 + idx];
  __syncthreads();

  const int c = tid & 127, rblk = tid >> 7;
  for (int q = 0; q < 8; ++q) {
    const int r = rblk + (q << 1);
    float a = sB1[c];
#pragma unroll 8
    for (int k = 0; k < 128; ++k) a = fmaf(sZ[r][k], sW[k * 128 + c], a);
    sT[r][c] = a > 0.0f ? a : 0.0f;
  }
  __syncthreads();
  for (int idx = tid; idx < 16384; idx += 256) sW[idx] = rW2[idx];
  __syncthreads();
  for (int q = 0; q < 8; ++q) {
    const int r = rblk + (q << 1);
    float a = sB2[c];
#pragma unroll 8
    for (int k = 0; k < 128; ++k) a = fmaf(sT[r][k], sW[k * 128 + c], a);
    a += sZ[r][c];
    sZ[r][c] = a > 0.0f ? a : 0.0f;
  }
  __syncthreads();
  for (int idx = tid; idx < 4096; idx += 256) sW[idx] = fW[idx];
  for (int idx = tid; idx < 1024; idx += 256) {
    sW[4096 + idx] = nW1[idx];
    sW[5120 + idx] = nW2[idx];
  }
  if (tid < 32) {
    sW[6144 + tid] = fb[tid];
    sW[6176 + tid] = ln_g[tid];
    sW[6208 + tid] = ln_b[tid];
    sW[6240 + tid] = nb1[tid];
    sW[6272 + tid] = nb2[tid];
  }
  __syncthreads();

  const int o = tid & 31, rr2 = tid >> 5;
  for (int g = 0; g < 2; ++g) {
    const int r = rr2 + (g << 3);
    float y = sW[6144 + o];
#pragma unroll 8
    for (int k = 0; k < 128; ++k) y = fmaf(sZ[r][k], sW[k * 32 + o], y);
    float mu = y;
#pragma unroll
    for (int m = 16; m >= 1; m >>= 1) mu += __shfl_xor(mu, m, 32);
    mu *= (1.0f / 32.0f);
    const float d = y - mu;
    float var = d * d;
#pragma unroll
    for (int m = 16; m >= 1; m >>= 1) var += __shfl_xor(var, m, 32);
    var *= (1.0f / 32.0f);
    const float yn = d * rsqrtf(var + 1e-5f) * sW[6176 + o] + sW[6208 + o];
    sY[r][o] = tanhf(yn);
  }
  __syncthreads();
  for (int g = 0; g < 2; ++g) {
    const int r = rr2 + (g << 3);
    float a = sW[6240 + o];
#pragma unroll
    for (int k = 0; k < 32; ++k) a = fmaf(sY[r][k], sW[4096 + k * 32 + o], a);
    sT2[r][o] = a > 0.0f ? a : 0.0f;
  }
  __syncthreads();
  for (int g = 0; g < 2; ++g) {
    const int r = rr2 + (g << 3);
    float a = sW[6272 + o];
#pragma unroll
    for (int k = 0; k < 32; ++k) a = fmaf(sT2[r][k], sW[5120 + k * 32 + o], a);
    out[(size_t)(rowbase + r) * 32 + o] = a;
  }
}

// ---------------------------------------------------------------------------
extern "C" void kernel_launch(void* const* d_in, const int* in_sizes, int n_in,
                              void* d_out, int out_size, void* d_ws, size_t ws_size,
                              hipStream_t stream) {
  const float* seq   = (const float*)d_in[0];
  const int*   adj   = (const int*)d_in[1];
  const float* Wih0  = (const float*)d_in[2];
  const float* Whh0  = (const float*)d_in[3];
  const float* bih0  = (const float*)d_in[4];
  const float* bhh0  = (const float*)d_in[5];
  const float* Wih1  = (const float*)d_in[6];
  const float* Whh1  = (const float*)d_in[7];
  const float* bih1  = (const float*)d_in[8];
  const float* bhh1  = (const float*)d_in[9];
  const float* gatW  = (const float*)d_in[10];
  const float* a_src = (const float*)d_in[11];
  const float* a_dst = (const float*)d_in[12];
  const float* rW1   = (const float*)d_in[13];
  const float* rb1   = (const float*)d_in[14];
  const float* rW2   = (const float*)d_in[15];
  const float* rb2   = (const float*)d_in[16];
  const float* fW    = (const float*)d_in[17];
  const float* fb    = (const float*)d_in[18];
  const float* ln_g  = (const float*)d_in[19];
  const float* ln_b  = (const float*)d_in[20];
  const float* nW1   = (const float*)d_in[21];
  const float* nb1   = (const float*)d_in[22];
  const float* nW2   = (const float*)d_in[23];
  const float* nb2   = (const float*)d_in[24];

  float* out  = (float*)d_out;                  // [BN][32] at offset 0
  float* attn = out + (size_t)BN * OO;          // [B,N,N,4] region (268MB)
  float* h1   = attn;                           // reuse attn region for h1

  float* ws   = (float*)d_ws;
  float* feat = ws;                             // [BN][64]
  float* Wh   = feat + (size_t)BN * 64;         // [BN][128]
  float* srcv = Wh + (size_t)BN * 128;          // [BN][4]
  float* dstv = srcv + (size_t)BN * 4;          // [BN][4]
  float* gat  = dstv + (size_t)BN * 4;          // [BN][128]

  gru_mfma_kernel<<<256, 512, 0, stream>>>(seq, Wih0, Whh0, bih0, bhh0, h1, nullptr);
  gru_mfma_kernel<<<256, 512, 0, stream>>>(h1, Wih1, Whh1, bih1, bhh1, nullptr, feat);
  gat_feat_kernel<<<2048, 256, 0, stream>>>(feat, gatW, a_src, a_dst, Wh, srcv, dstv);
  attn_kernel<<<512, 256, 0, stream>>>(Wh, srcv, dstv, adj, attn, gat);
  mlp_kernel<<<1024, 256, 0, stream>>>(gat, rW1, rb1, rW2, rb2, fW, fb,
                                       ln_g, ln_b, nW1, nb1, nW2, nb2, out);
}

// Round 5
// 440.211 us; speedup vs baseline: 3.9181x; 1.0571x over previous
//
#include <hip/hip_runtime.h>

// Problem constants
#define BB 16
#define TT 32
#define NN 1024
#define DD 64
#define HH 64
#define BN 16384          // B*N
#define GH 128
#define RR 128
#define OO 32

typedef __attribute__((ext_vector_type(8))) short short8;
typedef __attribute__((ext_vector_type(4))) float f32x4;

#define MFMA(A, B, C) __builtin_amdgcn_mfma_f32_16x16x32_bf16((A), (B), (C), 0, 0, 0)

__device__ __forceinline__ unsigned short f2bf(float x) {
  unsigned u = __float_as_uint(x);
  unsigned r = (u + 0x7FFFu + ((u >> 16) & 1u)) >> 16;
  return (unsigned short)r;
}
__device__ __forceinline__ float bf2f(unsigned short h) {
  return __uint_as_float(((unsigned)h) << 16);
}
__device__ __forceinline__ float sigmoid_fast(float x) {
  return 1.0f / (1.0f + __expf(-x));
}
__device__ __forceinline__ float tanh_fast(float x) {
  float e = __expf(2.0f * x);
  return 1.0f - 2.0f / (e + 1.0f);
}
__device__ __forceinline__ float leaky02(float x) {
  return fmaxf(x, 0.2f * x);
}

// ---------------------------------------------------------------------------
// MFMA GRU layer, v2: weight fragments hoisted to VGPRs (loop-invariant),
// loaded global->reg once. LDS only holds X (current step) and H (dbuf).
// Block = 256 thr = 4 waves, 32 sequences; wave w = j-group jt=w (16 cols),
// covering both 16-seq M-tiles. 512 blocks -> 2 blocks/CU (barrier overlap).
// Per step/wave: 16 ds_read_b128 (A-frags) + 72 MFMA (bf16x3 split).
// ---------------------------------------------------------------------------
__global__ __launch_bounds__(256, 2) void gru_mfma_kernel(
    const float* __restrict__ x,
    const float* __restrict__ Wih, const float* __restrict__ Whh,
    const float* __restrict__ bih, const float* __restrict__ bhh,
    float* __restrict__ h_all, float* __restrict__ h_last)
{
  __shared__ short sX[2][2048];      // [hi/lo][seq*64 + swz(k)] : 8 KB
  __shared__ short sH[2][2][2048];   // [buf][hi/lo][...] : 16 KB

  const int tid = threadIdx.x;
  const int gbase = blockIdx.x * 32;

  // ---- per-thread role decode ----
  const int jt = tid >> 6;           // wave id = 16-col j-group
  const int l = tid & 63;
  const int c = l & 15;
  const int rq = l >> 4;

  // ---- X(0) prefetch to regs ----
  const int sseq = tid >> 3;             // staging: thread -> (seq, 8-k chunk)
  const int sk0 = (tid & 7) << 3;
  const float* xrow = x + (size_t)(gbase + sseq) * (TT * 64) + sk0;
  float4 p0 = *reinterpret_cast<const float4*>(xrow);
  float4 p1 = *reinterpret_cast<const float4*>(xrow + 4);
  const int sxoff = sseq * 64 + (sk0 ^ ((sseq & 7) << 3));

  // ---- weight fragments: global -> reg, hi/lo split. [gate][src][ks] ----
  short8 wfh[3][2][2], wfl[3][2][2];
#pragma unroll
  for (int g = 0; g < 3; ++g) {
    const int row = g * 64 + jt * 16 + c;
#pragma unroll
    for (int ks = 0; ks < 2; ++ks) {
      const int col = ks * 32 + (rq << 3);
      float4 i0 = *reinterpret_cast<const float4*>(Wih + row * 64 + col);
      float4 i1 = *reinterpret_cast<const float4*>(Wih + row * 64 + col + 4);
      float4 h0 = *reinterpret_cast<const float4*>(Whh + row * 64 + col);
      float4 h1 = *reinterpret_cast<const float4*>(Whh + row * 64 + col + 4);
      float wi[8] = {i0.x, i0.y, i0.z, i0.w, i1.x, i1.y, i1.z, i1.w};
      float wh[8] = {h0.x, h0.y, h0.z, h0.w, h1.x, h1.y, h1.z, h1.w};
      short8 vih, vil, vhh, vhl;
#pragma unroll
      for (int e = 0; e < 8; ++e) {
        unsigned short hi = f2bf(wi[e]);
        vih[e] = (short)hi; vil[e] = (short)f2bf(wi[e] - bf2f(hi));
        unsigned short hh_ = f2bf(wh[e]);
        vhh[e] = (short)hh_; vhl[e] = (short)f2bf(wh[e] - bf2f(hh_));
      }
      wfh[g][0][ks] = vih; wfl[g][0][ks] = vil;
      wfh[g][1][ks] = vhh; wfl[g][1][ks] = vhl;
    }
  }

  // zero H buffer 0 (both planes)
  for (int i = tid; i < 2048; i += 256) { sH[0][0][i] = 0; sH[0][1][i] = 0; }

  // biases for this thread's j column
  const int jj = jt * 16 + c;
  const float br  = bih[jj]       + bhh[jj];
  const float bz  = bih[64 + jj]  + bhh[64 + jj];
  const float bni = bih[128 + jj];
  const float bnh = bhh[128 + jj];

  // A-fragment offsets for the two 16-seq M-tiles
  int ao[2][2];
#pragma unroll
  for (int mi = 0; mi < 2; ++mi) {
    const int arow = mi * 16 + c;
    const int asw = (arow & 7) << 3;
#pragma unroll
    for (int ks = 0; ks < 2; ++ks)
      ao[mi][ks] = arow * 64 + (((ks << 5) + (rq << 3)) ^ asw);
  }

  float h[2][4];
#pragma unroll
  for (int mi = 0; mi < 2; ++mi)
#pragma unroll
    for (int q = 0; q < 4; ++q) h[mi][q] = 0.0f;

  for (int t = 0; t < TT; ++t) {
    float4 n0 = p0, n1 = p1;
    if (t + 1 < TT) {
      n0 = *reinterpret_cast<const float4*>(xrow + (t + 1) * 64);
      n1 = *reinterpret_cast<const float4*>(xrow + (t + 1) * 64 + 4);
    }
    __syncthreads();   // prior step's reads of sX done
    {
      float xs[8] = {p0.x, p0.y, p0.z, p0.w, p1.x, p1.y, p1.z, p1.w};
      short8 vh, vl;
#pragma unroll
      for (int e = 0; e < 8; ++e) {
        unsigned short hh_ = f2bf(xs[e]);
        vh[e] = (short)hh_; vl[e] = (short)f2bf(xs[e] - bf2f(hh_));
      }
      *reinterpret_cast<short8*>(&sX[0][sxoff]) = vh;
      *reinterpret_cast<short8*>(&sX[1][sxoff]) = vl;
    }
    p0 = n0; p1 = n1;
    __syncthreads();   // X(t) + H(t) visible

    const int cb = t & 1, nb = (t + 1) & 1;

    // A-fragments (only per-step LDS reads: 16 x ds_read_b128)
    short8 xhf[2][2], xlf[2][2], hhf[2][2], hlf[2][2];
#pragma unroll
    for (int mi = 0; mi < 2; ++mi)
#pragma unroll
      for (int ks = 0; ks < 2; ++ks) {
        xhf[mi][ks] = *reinterpret_cast<const short8*>(&sX[0][ao[mi][ks]]);
        xlf[mi][ks] = *reinterpret_cast<const short8*>(&sX[1][ao[mi][ks]]);
        hhf[mi][ks] = *reinterpret_cast<const short8*>(&sH[cb][0][ao[mi][ks]]);
        hlf[mi][ks] = *reinterpret_cast<const short8*>(&sH[cb][1][ao[mi][ks]]);
      }

    f32x4 accr[2], accz[2], accni[2], accnh[2];
#pragma unroll
    for (int mi = 0; mi < 2; ++mi) {
      accr[mi]  = (f32x4){br, br, br, br};
      accz[mi]  = (f32x4){bz, bz, bz, bz};
      accni[mi] = (f32x4){bni, bni, bni, bni};
      accnh[mi] = (f32x4){bnh, bnh, bnh, bnh};
    }

#pragma unroll
    for (int mi = 0; mi < 2; ++mi)
#pragma unroll
      for (int ks = 0; ks < 2; ++ks) {
        // r gate (gi+gh share acc)
        accr[mi] = MFMA(xhf[mi][ks], wfh[0][0][ks], accr[mi]);
        accr[mi] = MFMA(xhf[mi][ks], wfl[0][0][ks], accr[mi]);
        accr[mi] = MFMA(xlf[mi][ks], wfh[0][0][ks], accr[mi]);
        accr[mi] = MFMA(hhf[mi][ks], wfh[0][1][ks], accr[mi]);
        accr[mi] = MFMA(hhf[mi][ks], wfl[0][1][ks], accr[mi]);
        accr[mi] = MFMA(hlf[mi][ks], wfh[0][1][ks], accr[mi]);
        // z gate
        accz[mi] = MFMA(xhf[mi][ks], wfh[1][0][ks], accz[mi]);
        accz[mi] = MFMA(xhf[mi][ks], wfl[1][0][ks], accz[mi]);
        accz[mi] = MFMA(xlf[mi][ks], wfh[1][0][ks], accz[mi]);
        accz[mi] = MFMA(hhf[mi][ks], wfh[1][1][ks], accz[mi]);
        accz[mi] = MFMA(hhf[mi][ks], wfl[1][1][ks], accz[mi]);
        accz[mi] = MFMA(hlf[mi][ks], wfh[1][1][ks], accz[mi]);
        // n gate: gi and gh separate
        accni[mi] = MFMA(xhf[mi][ks], wfh[2][0][ks], accni[mi]);
        accni[mi] = MFMA(xhf[mi][ks], wfl[2][0][ks], accni[mi]);
        accni[mi] = MFMA(xlf[mi][ks], wfh[2][0][ks], accni[mi]);
        accnh[mi] = MFMA(hhf[mi][ks], wfh[2][1][ks], accnh[mi]);
        accnh[mi] = MFMA(hhf[mi][ks], wfl[2][1][ks], accnh[mi]);
        accnh[mi] = MFMA(hlf[mi][ks], wfh[2][1][ks], accnh[mi]);
      }

    // gates + H(t+1) write + optional h_all store
#pragma unroll
    for (int mi = 0; mi < 2; ++mi) {
#pragma unroll
      for (int q = 0; q < 4; ++q) {
        float rg = sigmoid_fast(accr[mi][q]);
        float zg = sigmoid_fast(accz[mi][q]);
        float ng = tanh_fast(fmaf(rg, accnh[mi][q], accni[mi][q]));
        float hv = (1.0f - zg) * ng + zg * h[mi][q];
        h[mi][q] = hv;
        const int seq = mi * 16 + (rq << 2) + q;
        const int hoff = seq * 64 + (jj ^ ((seq & 7) << 3));
        unsigned short hh_ = f2bf(hv);
        sH[nb][0][hoff] = (short)hh_;
        sH[nb][1][hoff] = (short)f2bf(hv - bf2f(hh_));
        if (h_all)
          h_all[(size_t)(gbase + seq) * (TT * 64) + t * 64 + jj] = hv;
      }
    }
  }

  if (h_last) {
#pragma unroll
    for (int mi = 0; mi < 2; ++mi)
#pragma unroll
      for (int q = 0; q < 4; ++q) {
        const int seq = mi * 16 + (rq << 2) + q;
        h_last[(size_t)(gbase + seq) * 64 + jj] = h[mi][q];
      }
  }
}

// ---------------------------------------------------------------------------
// GAT projection (unchanged).
// ---------------------------------------------------------------------------
__global__ __launch_bounds__(256) void gat_feat_kernel(
    const float* __restrict__ feat, const float* __restrict__ gatW,
    const float* __restrict__ a_src, const float* __restrict__ a_dst,
    float* __restrict__ Wh, float* __restrict__ srcv, float* __restrict__ dstv)
{
  __shared__ float sGatW[64 * 128];
  __shared__ float sFeat[8][64];
  __shared__ float sAs[128], sAd[128];
  const int tid = threadIdx.x;
  const int rowbase = blockIdx.x * 8;
  for (int idx = tid; idx < 8192; idx += 256) sGatW[idx] = gatW[idx];
  if (tid < 128) { sAs[tid] = a_src[tid]; sAd[tid] = a_dst[tid]; }
  for (int idx = tid; idx < 512; idx += 256)
    sFeat[idx >> 6][idx & 63] = feat[(size_t)rowbase * 64 + idx];
  __syncthreads();

  const int hf = tid & 127, half = tid >> 7;
  const int h = hf >> 5;
  const float as = sAs[hf], ad = sAd[hf];
  for (int rr = half; rr < 8; rr += 2) {
    float acc = 0.0f;
#pragma unroll 8
    for (int k = 0; k < 64; ++k) acc = fmaf(sFeat[rr][k], sGatW[k * 128 + hf], acc);
    const size_t grow = rowbase + rr;
    Wh[grow * 128 + hf] = acc;
    float ps = acc * as, pd = acc * ad;
#pragma unroll
    for (int m = 16; m >= 1; m >>= 1) {
      ps += __shfl_xor(ps, m, 32);
      pd += __shfl_xor(pd, m, 32);
    }
    if ((hf & 31) == 0) {
      srcv[grow * 4 + h] = ps;
      dstv[grow * 4 + h] = pd;
    }
  }
}

// ---------------------------------------------------------------------------
// Attention + gat aggregation (unchanged from R3).
// ---------------------------------------------------------------------------
__global__ __launch_bounds__(256) void attn_kernel(
    const float* __restrict__ Wh, const float* __restrict__ srcp,
    const float* __restrict__ dstp, const int* __restrict__ adj,
    float* __restrict__ attn_out, float* __restrict__ gat_out)
{
  __shared__ __align__(16) float sDst[4096];          // 16 KB
  __shared__ __align__(16) float sSrc[128];
  __shared__ __align__(16) float sIS[128];            // 1/sum (or -1 sentinel)
  __shared__ unsigned int sAdjW[32][32];              // 4 KB bitmask
  __shared__ __align__(16) unsigned short sPhi[4][32][40];  // 10 KB
  __shared__ __align__(16) unsigned short sPlo[4][32][40];  // 10 KB
  __shared__ __align__(16) unsigned short sBhi[4][32][40];  // 10 KB
  __shared__ __align__(16) unsigned short sBlo[4][32][40];  // 10 KB

  const int tid = threadIdx.x;
  const int bid = blockIdx.x;
  const int swzb = ((bid & 7) << 6) | (bid >> 3);     // XCD-cluster swizzle
  const int b = swzb >> 5;
  const int itile = (swzb & 31) << 5;

  // ---- stage dst, src ----
  for (int idx = tid; idx < 4096; idx += 256) sDst[idx] = dstp[(size_t)b * 4096 + idx];
  if (tid < 128) sSrc[tid] = srcp[((size_t)b * 1024 + itile) * 4 + tid];

  // ---- build adj bitmask: thread -> (row=tid>>3, 4 words) ----
  {
    const int row = tid >> 3;
    const int w0 = (tid & 7) << 2;
    const int* arow_g = adj + (size_t)(itile + row) * 1024 + (w0 << 5);
#pragma unroll
    for (int wq = 0; wq < 4; ++wq) {
      unsigned int word = 0;
#pragma unroll
      for (int c4 = 0; c4 < 8; ++c4) {
        int4 v = *reinterpret_cast<const int4*>(arow_g + (wq << 5) + (c4 << 2));
        word |= (unsigned)((v.x != 0) ? 1 : 0) << (c4 * 4 + 0);
        word |= (unsigned)((v.y != 0) ? 1 : 0) << (c4 * 4 + 1);
        word |= (unsigned)((v.z != 0) ? 1 : 0) << (c4 * 4 + 2);
        word |= (unsigned)((v.w != 0) ? 1 : 0) << (c4 * 4 + 3);
      }
      sAdjW[row][w0 + wq] = word;
    }
  }
  __syncthreads();

  // ---- pass 1: s[i][h] = sum_j mask*exp(leaky(src+dst)), m=0 ----
  {
    const int i = tid >> 3;          // 0..31
    const int par = tid & 7;         // 8-way j split
    const float4 sv = *reinterpret_cast<const float4*>(&sSrc[i * 4]);
    f32x4 acc = (f32x4){0.f, 0.f, 0.f, 0.f};
    const unsigned int bit0 = 1u << par;
    for (int kw = 0; kw < 32; ++kw) {
      const unsigned int word = sAdjW[i][kw];
#pragma unroll
      for (int e = 0; e < 4; ++e) {
        const int gj = (kw << 5) + (e << 3) + par;
        const float4 dv = *reinterpret_cast<const float4*>(&sDst[gj * 4]);
        const float mf = (word & (bit0 << (e << 3))) ? 1.0f : 0.0f;
        acc[0] = fmaf(mf, __expf(leaky02(sv.x + dv.x)), acc[0]);
        acc[1] = fmaf(mf, __expf(leaky02(sv.y + dv.y)), acc[1]);
        acc[2] = fmaf(mf, __expf(leaky02(sv.z + dv.z)), acc[2]);
        acc[3] = fmaf(mf, __expf(leaky02(sv.w + dv.w)), acc[3]);
      }
    }
#pragma unroll
    for (int m = 1; m < 8; m <<= 1) {
#pragma unroll
      for (int q = 0; q < 4; ++q) acc[q] += __shfl_xor(acc[q], m, 64);
    }
    if (par == 0) {
      float4 isv;
      isv.x = acc[0] > 0.f ? 1.0f / acc[0] : -1.0f;
      isv.y = acc[1] > 0.f ? 1.0f / acc[1] : -1.0f;
      isv.z = acc[2] > 0.f ? 1.0f / acc[2] : -1.0f;
      isv.w = acc[3] > 0.f ? 1.0f / acc[3] : -1.0f;
      *reinterpret_cast<float4*>(&sIS[i * 4]) = isv;
    }
  }
  __syncthreads();

  // ---- pass 2: 32 j-tiles of 32 ----
  const int il = tid >> 3;          // 0..31 (i row)
  const int jsub = tid & 7;
  const int wv = tid >> 6;          // wave id = head for MFMA phase
  const int l = tid & 63;
  const int jjB = tid & 31;         // B-staging: Wh row within tile
  const int fcB = tid >> 5;         // B-staging: 16-hf chunk

  const float4 sv4 = *reinterpret_cast<const float4*>(&sSrc[il * 4]);
  const float4 is4 = *reinterpret_cast<const float4*>(&sIS[il * 4]);
  f32x4* arow_out = reinterpret_cast<f32x4*>(
      attn_out + ((size_t)(b * 1024 + itile + il)) * 4096);

  f32x4 accg[2][2];
#pragma unroll
  for (int m = 0; m < 2; ++m)
#pragma unroll
    for (int n = 0; n < 2; ++n) accg[m][n] = (f32x4){0.f, 0.f, 0.f, 0.f};

  // A/B fragment LDS offsets (element index into [32][40] plane)
  const int frow = l & 15, fchunk = l >> 4;
  const int wplane = wv * (32 * 40);

  for (int jt = 0; jt < 32; ++jt) {
    const int j0 = jt << 5;
    // -- compute & write phase --
    {
      const unsigned int word = sAdjW[il][jt];
#pragma unroll
      for (int q = 0; q < 4; ++q) {
        const int j = jsub + (q << 3);
        const int gj = j0 + j;
        const float4 dv = *reinterpret_cast<const float4*>(&sDst[gj * 4]);
        const float mf = (word & (1u << j)) ? 1.0f : 0.0f;
        f32x4 a4;
        float ex;
        ex = mf * __expf(leaky02(sv4.x + dv.x)); a4[0] = ex * is4.x; if (is4.x < 0.f) a4[0] = 9.765625e-4f;
        ex = mf * __expf(leaky02(sv4.y + dv.y)); a4[1] = ex * is4.y; if (is4.y < 0.f) a4[1] = 9.765625e-4f;
        ex = mf * __expf(leaky02(sv4.z + dv.z)); a4[2] = ex * is4.z; if (is4.z < 0.f) a4[2] = 9.765625e-4f;
        ex = mf * __expf(leaky02(sv4.w + dv.w)); a4[3] = ex * is4.w; if (is4.w < 0.f) a4[3] = 9.765625e-4f;
        __builtin_nontemporal_store(a4, &arow_out[gj]);
        float av[4] = {a4[0], a4[1], a4[2], a4[3]};
#pragma unroll
        for (int h = 0; h < 4; ++h) {
          unsigned short hi = f2bf(av[h]);
          sPhi[h][il][j] = hi;
          sPlo[h][il][j] = f2bf(av[h] - bf2f(hi));
        }
      }
      // B staging: Wh[j0+jjB][fcB*16..+16] -> sB[h][f][jjB]
      const float* wrow = Wh + ((size_t)(b * 1024 + j0 + jjB)) * 128 + (fcB << 4);
#pragma unroll
      for (int c4 = 0; c4 < 4; ++c4) {
        float4 v = *reinterpret_cast<const float4*>(wrow + (c4 << 2));
        float vv[4] = {v.x, v.y, v.z, v.w};
#pragma unroll
        for (int e = 0; e < 4; ++e) {
          const int hf = (fcB << 4) + (c4 << 2) + e;
          const int h = hf >> 5, f = hf & 31;
          unsigned short hi = f2bf(vv[e]);
          sBhi[h][f][jjB] = hi;
          sBlo[h][f][jjB] = f2bf(vv[e] - bf2f(hi));
        }
      }
    }
    __syncthreads();
    // -- MFMA phase: wave wv handles head wv --
    {
      short8 ahi[2], alo[2], bhi[2], blo[2];
#pragma unroll
      for (int m = 0; m < 2; ++m) {
        const int ro = wplane + (m * 16 + frow) * 40 + fchunk * 8;
        ahi[m] = *reinterpret_cast<const short8*>(&sPhi[0][0][0] + ro);
        alo[m] = *reinterpret_cast<const short8*>(&sPlo[0][0][0] + ro);
      }
#pragma unroll
      for (int n = 0; n < 2; ++n) {
        const int ro = wplane + (n * 16 + frow) * 40 + fchunk * 8;
        bhi[n] = *reinterpret_cast<const short8*>(&sBhi[0][0][0] + ro);
        blo[n] = *reinterpret_cast<const short8*>(&sBlo[0][0][0] + ro);
      }
#pragma unroll
      for (int m = 0; m < 2; ++m)
#pragma unroll
        for (int n = 0; n < 2; ++n) {
          accg[m][n] = MFMA(ahi[m], bhi[n], accg[m][n]);
          accg[m][n] = MFMA(ahi[m], blo[n], accg[m][n]);
          accg[m][n] = MFMA(alo[m], bhi[n], accg[m][n]);
        }
    }
    __syncthreads();
  }

  // ---- epilogue: elu + store gat ----
#pragma unroll
  for (int m = 0; m < 2; ++m)
#pragma unroll
    for (int n = 0; n < 2; ++n)
#pragma unroll
      for (int q = 0; q < 4; ++q) {
        const int i = m * 16 + (l >> 4) * 4 + q;
        const int f = n * 16 + (l & 15);
        float v = accg[m][n][q];
        v = v > 0.0f ? v : (__expf(v) - 1.0f);
        gat_out[((size_t)(b * 1024 + itile + i)) * 128 + wv * 32 + f] = v;
      }
}

// ---------------------------------------------------------------------------
// MLP chain (unchanged).
// ---------------------------------------------------------------------------
__global__ __launch_bounds__(256) void mlp_kernel(
    const float* __restrict__ gat,
    const float* __restrict__ rW1, const float* __restrict__ rb1,
    const float* __restrict__ rW2, const float* __restrict__ rb2,
    const float* __restrict__ fW,  const float* __restrict__ fb,
    const float* __restrict__ ln_g, const float* __restrict__ ln_b,
    const float* __restrict__ nW1, const float* __restrict__ nb1,
    const float* __restrict__ nW2, const float* __restrict__ nb2,
    float* __restrict__ out)
{
  __shared__ float sW[128 * 128];
  __shared__ float sZ[16][128];
  __shared__ float sT[16][128];
  __shared__ float sY[16][32];
  __shared__ float sT2[16][32];
  __shared__ float sB1[128], sB2[128];

  const int tid = threadIdx.x;
  const int rowbase = blockIdx.x * 16;

  for (int idx = tid; idx < 16384; idx += 256) sW[idx] = rW1[idx];
  if (tid < 128) { sB1[tid] = rb1[tid]; sB2[tid] = rb2[tid]; }
  for (int idx = tid; idx < 2048; idx += 256)
    sZ[idx >> 7][idx & 127] = gat[(size_t)rowbase * 128 + idx];
  __syncthreads();

  const int c = tid & 127, rblk = tid >> 7;
  for (int q = 0; q < 8; ++q) {
    const int r = rblk + (q << 1);
    float a = sB1[c];
#pragma unroll 8
    for (int k = 0; k < 128; ++k) a = fmaf(sZ[r][k], sW[k * 128 + c], a);
    sT[r][c] = a > 0.0f ? a : 0.0f;
  }
  __syncthreads();
  for (int idx = tid; idx < 16384; idx += 256) sW[idx] = rW2[idx];
  __syncthreads();
  for (int q = 0; q < 8; ++q) {
    const int r = rblk + (q << 1);
    float a = sB2[c];
#pragma unroll 8
    for (int k = 0; k < 128; ++k) a = fmaf(sT[r][k], sW[k * 128 + c], a);
    a += sZ[r][c];
    sZ[r][c] = a > 0.0f ? a : 0.0f;
  }
  __syncthreads();
  for (int idx = tid; idx < 4096; idx += 256) sW[idx] = fW[idx];
  for (int idx = tid; idx < 1024; idx += 256) {
    sW[4096 + idx] = nW1[idx];
    sW[5120 + idx] = nW2[idx];
  }
  if (tid < 32) {
    sW[6144 + tid] = fb[tid];
    sW[6176 + tid] = ln_g[tid];
    sW[6208 + tid] = ln_b[tid];
    sW[6240 + tid] = nb1[tid];
    sW[6272 + tid] = nb2[tid];
  }
  __syncthreads();

  const int o = tid & 31, rr2 = tid >> 5;
  for (int g = 0; g < 2; ++g) {
    const int r = rr2 + (g << 3);
    float y = sW[6144 + o];
#pragma unroll 8
    for (int k = 0; k < 128; ++k) y = fmaf(sZ[r][k], sW[k * 32 + o], y);
    float mu = y;
#pragma unroll
    for (int m = 16; m >= 1; m >>= 1) mu += __shfl_xor(mu, m, 32);
    mu *= (1.0f / 32.0f);
    const float d = y - mu;
    float var = d * d;
#pragma unroll
    for (int m = 16; m >= 1; m >>= 1) var += __shfl_xor(var, m, 32);
    var *= (1.0f / 32.0f);
    const float yn = d * rsqrtf(var + 1e-5f) * sW[6176 + o] + sW[6208 + o];
    sY[r][o] = tanhf(yn);
  }
  __syncthreads();
  for (int g = 0; g < 2; ++g) {
    const int r = rr2 + (g << 3);
    float a = sW[6240 + o];
#pragma unroll
    for (int k = 0; k < 32; ++k) a = fmaf(sY[r][k], sW[4096 + k * 32 + o], a);
    sT2[r][o] = a > 0.0f ? a : 0.0f;
  }
  __syncthreads();
  for (int g = 0; g < 2; ++g) {
    const int r = rr2 + (g << 3);
    float a = sW[6272 + o];
#pragma unroll
    for (int k = 0; k < 32; ++k) a = fmaf(sT2[r][k], sW[5120 + k * 32 + o], a);
    out[(size_t)(rowbase + r) * 32 + o] = a;
  }
}

// ---------------------------------------------------------------------------
extern "C" void kernel_launch(void* const* d_in, const int* in_sizes, int n_in,
                              void* d_out, int out_size, void* d_ws, size_t ws_size,
                              hipStream_t stream) {
  const float* seq   = (const float*)d_in[0];
  const int*   adj   = (const int*)d_in[1];
  const float* Wih0  = (const float*)d_in[2];
  const float* Whh0  = (const float*)d_in[3];
  const float* bih0  = (const float*)d_in[4];
  const float* bhh0  = (const float*)d_in[5];
  const float* Wih1  = (const float*)d_in[6];
  const float* Whh1  = (const float*)d_in[7];
  const float* bih1  = (const float*)d_in[8];
  const float* bhh1  = (const float*)d_in[9];
  const float* gatW  = (const float*)d_in[10];
  const float* a_src = (const float*)d_in[11];
  const float* a_dst = (const float*)d_in[12];
  const float* rW1   = (const float*)d_in[13];
  const float* rb1   = (const float*)d_in[14];
  const float* rW2   = (const float*)d_in[15];
  const float* rb2   = (const float*)d_in[16];
  const float* fW    = (const float*)d_in[17];
  const float* fb    = (const float*)d_in[18];
  const float* ln_g  = (const float*)d_in[19];
  const float* ln_b  = (const float*)d_in[20];
  const float* nW1   = (const float*)d_in[21];
  const float* nb1   = (const float*)d_in[22];
  const float* nW2   = (const float*)d_in[23];
  const float* nb2   = (const float*)d_in[24];

  float* out  = (float*)d_out;                  // [BN][32] at offset 0
  float* attn = out + (size_t)BN * OO;          // [B,N,N,4] region (268MB)
  float* h1   = attn;                           // reuse attn region for h1

  float* ws   = (float*)d_ws;
  float* feat = ws;                             // [BN][64]
  float* Wh   = feat + (size_t)BN * 64;         // [BN][128]
  float* srcv = Wh + (size_t)BN * 128;          // [BN][4]
  float* dstv = srcv + (size_t)BN * 4;          // [BN][4]
  float* gat  = dstv + (size_t)BN * 4;          // [BN][128]

  gru_mfma_kernel<<<512, 256, 0, stream>>>(seq, Wih0, Whh0, bih0, bhh0, h1, nullptr);
  gru_mfma_kernel<<<512, 256, 0, stream>>>(h1, Wih1, Whh1, bih1, bhh1, nullptr, feat);
  gat_feat_kernel<<<2048, 256, 0, stream>>>(feat, gatW, a_src, a_dst, Wh, srcv, dstv);
  attn_kernel<<<512, 256, 0, stream>>>(Wh, srcv, dstv, adj, attn, gat);
  mlp_kernel<<<1024, 256, 0, stream>>>(gat, rW1, rb1, rW2, rb2, fW, fb,
                                       ln_g, ln_b, nW1, nb1, nW2, nb2, out);
}

// Round 6
// 427.699 us; speedup vs baseline: 4.0327x; 1.0293x over previous
//
#include <hip/hip_runtime.h>

// Problem constants
#define BB 16
#define TT 32
#define NN 1024
#define DD 64
#define HH 64
#define BN 16384          // B*N
#define GH 128
#define RR 128
#define OO 32

typedef __attribute__((ext_vector_type(8))) short short8;
typedef __attribute__((ext_vector_type(4))) float f32x4;

#define MFMA(A, B, C) __builtin_amdgcn_mfma_f32_16x16x32_bf16((A), (B), (C), 0, 0, 0)

__device__ __forceinline__ unsigned short f2bf(float x) {
  unsigned u = __float_as_uint(x);
  unsigned r = (u + 0x7FFFu + ((u >> 16) & 1u)) >> 16;
  return (unsigned short)r;
}
__device__ __forceinline__ float bf2f(unsigned short h) {
  return __uint_as_float(((unsigned)h) << 16);
}
__device__ __forceinline__ float sigmoid_fast(float x) {
  return 1.0f / (1.0f + __expf(-x));
}
__device__ __forceinline__ float tanh_fast(float x) {
  float e = __expf(2.0f * x);
  return 1.0f - 2.0f / (e + 1.0f);
}
__device__ __forceinline__ float leaky02(float x) {
  return fmaxf(x, 0.2f * x);
}

// ---------------------------------------------------------------------------
// Fused 2-layer MFMA GRU. Block = 512 thr = 8 waves, 32 sequences.
// Wave w: layer = w>>2, jt = w&3 (16 output cols). Layer-1 runs 1 step
// behind layer-0 and reads its input h0(t) straight from layer-0's LDS
// H buffer -- no h_all global round-trip. Weight frags in VGPRs (96/wave);
// A-frags loaded per-ks to keep VGPR < 256. t = 0..32 with activity guards.
// ---------------------------------------------------------------------------
__global__ __launch_bounds__(512, 2) void gru_fused_kernel(
    const float* __restrict__ x,
    const float* __restrict__ Wih0, const float* __restrict__ Whh0,
    const float* __restrict__ bih0, const float* __restrict__ bhh0,
    const float* __restrict__ Wih1, const float* __restrict__ Whh1,
    const float* __restrict__ bih1, const float* __restrict__ bhh1,
    float* __restrict__ feat)
{
  __shared__ short sX[2][2048];        // [plane][seq*64 + swz(k)] : 8 KB
  __shared__ short sH0[2][2][2048];    // [buf][plane][...] : 16 KB
  __shared__ short sH1[2][2][2048];    // [buf][plane][...] : 16 KB

  const int tid = threadIdx.x;
  const int gbase = blockIdx.x * 32;

  const int w = tid >> 6, l = tid & 63;
  const int layer = w >> 2;            // 0 or 1
  const int jt = w & 3;                // 16-col j-group
  const int c = l & 15;
  const int rq = l >> 4;

  const float* Wih = layer ? Wih1 : Wih0;
  const float* Whh = layer ? Whh1 : Whh0;
  const float* bihp = layer ? bih1 : bih0;
  const float* bhhp = layer ? bhh1 : bhh0;

  // ---- weight fragments: global -> reg, hi/lo split. [gate][src][ks] ----
  short8 wfh[3][2][2], wfl[3][2][2];
#pragma unroll
  for (int g = 0; g < 3; ++g) {
    const int row = g * 64 + jt * 16 + c;
#pragma unroll
    for (int ks = 0; ks < 2; ++ks) {
      const int col = ks * 32 + (rq << 3);
      float4 i0 = *reinterpret_cast<const float4*>(Wih + row * 64 + col);
      float4 i1 = *reinterpret_cast<const float4*>(Wih + row * 64 + col + 4);
      float4 h0 = *reinterpret_cast<const float4*>(Whh + row * 64 + col);
      float4 h1 = *reinterpret_cast<const float4*>(Whh + row * 64 + col + 4);
      float wi[8] = {i0.x, i0.y, i0.z, i0.w, i1.x, i1.y, i1.z, i1.w};
      float wh[8] = {h0.x, h0.y, h0.z, h0.w, h1.x, h1.y, h1.z, h1.w};
      short8 vih, vil, vhh, vhl;
#pragma unroll
      for (int e = 0; e < 8; ++e) {
        unsigned short hi = f2bf(wi[e]);
        vih[e] = (short)hi; vil[e] = (short)f2bf(wi[e] - bf2f(hi));
        unsigned short hh_ = f2bf(wh[e]);
        vhh[e] = (short)hh_; vhl[e] = (short)f2bf(wh[e] - bf2f(hh_));
      }
      wfh[g][0][ks] = vih; wfl[g][0][ks] = vil;
      wfh[g][1][ks] = vhh; wfl[g][1][ks] = vhl;
    }
  }

  // ---- X(0) prefetch (layer-0 threads = tid<256) ----
  const int sseq = tid >> 3;
  const int sk0 = (tid & 7) << 3;
  const float* xrow = x + (size_t)(gbase + (sseq & 31)) * (TT * 64) + sk0;
  float4 p0 = {0.f, 0.f, 0.f, 0.f}, p1 = {0.f, 0.f, 0.f, 0.f};
  if (tid < 256) {
    p0 = *reinterpret_cast<const float4*>(xrow);
    p1 = *reinterpret_cast<const float4*>(xrow + 4);
  }
  const int sxoff = (sseq & 31) * 64 + (sk0 ^ (((sseq & 31) & 7) << 3));

  // zero-init H buffers (both layers, buf 0, both planes)
  for (int i = tid; i < 2048; i += 512) {
    sH0[0][0][i] = 0; sH0[0][1][i] = 0;
    sH1[0][0][i] = 0; sH1[0][1][i] = 0;
  }

  // biases for this thread's j column (its layer)
  const int jj = jt * 16 + c;
  const float br  = bihp[jj]       + bhhp[jj];
  const float bz  = bihp[64 + jj]  + bhhp[64 + jj];
  const float bni = bihp[128 + jj];
  const float bnh = bhhp[128 + jj];

  // A-fragment offsets for the two 16-seq M-tiles
  int ao[2][2];
#pragma unroll
  for (int mi = 0; mi < 2; ++mi) {
    const int arow = mi * 16 + c;
    const int asw = (arow & 7) << 3;
#pragma unroll
    for (int ks = 0; ks < 2; ++ks)
      ao[mi][ks] = arow * 64 + (((ks << 5) + (rq << 3)) ^ asw);
  }

  float h[2][4];
#pragma unroll
  for (int mi = 0; mi < 2; ++mi)
#pragma unroll
    for (int q = 0; q < 4; ++q) h[mi][q] = 0.0f;

  for (int t = 0; t <= TT; ++t) {
    // prefetch X(t+1) to regs (layer-0 staging threads)
    float4 n0, n1;
    const bool pf = (tid < 256) && (t + 1 < TT);
    if (pf) {
      n0 = *reinterpret_cast<const float4*>(xrow + (t + 1) * 64);
      n1 = *reinterpret_cast<const float4*>(xrow + (t + 1) * 64 + 4);
    }
    __syncthreads();   // prior step's reads of sX done
    if (tid < 256 && t < TT) {
      float xs[8] = {p0.x, p0.y, p0.z, p0.w, p1.x, p1.y, p1.z, p1.w};
      short8 vh, vl;
#pragma unroll
      for (int e = 0; e < 8; ++e) {
        unsigned short hh_ = f2bf(xs[e]);
        vh[e] = (short)hh_; vl[e] = (short)f2bf(xs[e] - bf2f(hh_));
      }
      *reinterpret_cast<short8*>(&sX[0][sxoff]) = vh;
      *reinterpret_cast<short8*>(&sX[1][sxoff]) = vl;
    }
    if (pf) { p0 = n0; p1 = n1; }
    __syncthreads();   // X(t), H buffers visible

    const int cb = t & 1, nb = (t + 1) & 1;
    const bool active = (layer == 0) ? (t < TT) : (t >= 1);
    if (active) {
      // source selection (wave-uniform)
      const short *xsrc0, *xsrc1, *hsrc0, *hsrc1;
      if (layer == 0) {
        xsrc0 = &sX[0][0];       xsrc1 = &sX[1][0];
        hsrc0 = &sH0[cb][0][0];  hsrc1 = &sH0[cb][1][0];
      } else {
        xsrc0 = &sH0[cb][0][0];  xsrc1 = &sH0[cb][1][0];
        hsrc0 = &sH1[nb][0][0];  hsrc1 = &sH1[nb][1][0];
      }

      f32x4 accr[2], accz[2], accni[2], accnh[2];
#pragma unroll
      for (int mi = 0; mi < 2; ++mi) {
        accr[mi]  = (f32x4){br, br, br, br};
        accz[mi]  = (f32x4){bz, bz, bz, bz};
        accni[mi] = (f32x4){bni, bni, bni, bni};
        accnh[mi] = (f32x4){bnh, bnh, bnh, bnh};
      }

#pragma unroll
      for (int ks = 0; ks < 2; ++ks) {
        short8 xhf[2], xlf[2], hhf[2], hlf[2];
#pragma unroll
        for (int mi = 0; mi < 2; ++mi) {
          xhf[mi] = *reinterpret_cast<const short8*>(xsrc0 + ao[mi][ks]);
          xlf[mi] = *reinterpret_cast<const short8*>(xsrc1 + ao[mi][ks]);
          hhf[mi] = *reinterpret_cast<const short8*>(hsrc0 + ao[mi][ks]);
          hlf[mi] = *reinterpret_cast<const short8*>(hsrc1 + ao[mi][ks]);
        }
#pragma unroll
        for (int mi = 0; mi < 2; ++mi) {
          // r gate (gi+gh share acc)
          accr[mi] = MFMA(xhf[mi], wfh[0][0][ks], accr[mi]);
          accr[mi] = MFMA(xhf[mi], wfl[0][0][ks], accr[mi]);
          accr[mi] = MFMA(xlf[mi], wfh[0][0][ks], accr[mi]);
          accr[mi] = MFMA(hhf[mi], wfh[0][1][ks], accr[mi]);
          accr[mi] = MFMA(hhf[mi], wfl[0][1][ks], accr[mi]);
          accr[mi] = MFMA(hlf[mi], wfh[0][1][ks], accr[mi]);
          // z gate
          accz[mi] = MFMA(xhf[mi], wfh[1][0][ks], accz[mi]);
          accz[mi] = MFMA(xhf[mi], wfl[1][0][ks], accz[mi]);
          accz[mi] = MFMA(xlf[mi], wfh[1][0][ks], accz[mi]);
          accz[mi] = MFMA(hhf[mi], wfh[1][1][ks], accz[mi]);
          accz[mi] = MFMA(hhf[mi], wfl[1][1][ks], accz[mi]);
          accz[mi] = MFMA(hlf[mi], wfh[1][1][ks], accz[mi]);
          // n gate: gi and gh separate
          accni[mi] = MFMA(xhf[mi], wfh[2][0][ks], accni[mi]);
          accni[mi] = MFMA(xhf[mi], wfl[2][0][ks], accni[mi]);
          accni[mi] = MFMA(xlf[mi], wfh[2][0][ks], accni[mi]);
          accnh[mi] = MFMA(hhf[mi], wfh[2][1][ks], accnh[mi]);
          accnh[mi] = MFMA(hhf[mi], wfl[2][1][ks], accnh[mi]);
          accnh[mi] = MFMA(hlf[mi], wfh[2][1][ks], accnh[mi]);
        }
      }

      // gates + H write (layer0 -> sH0[nb], layer1 -> sH1[cb])
      short* dsthi = layer ? &sH1[cb][0][0] : &sH0[nb][0][0];
      short* dstlo = layer ? &sH1[cb][1][0] : &sH0[nb][1][0];
#pragma unroll
      for (int mi = 0; mi < 2; ++mi) {
#pragma unroll
        for (int q = 0; q < 4; ++q) {
          float rg = sigmoid_fast(accr[mi][q]);
          float zg = sigmoid_fast(accz[mi][q]);
          float ng = tanh_fast(fmaf(rg, accnh[mi][q], accni[mi][q]));
          float hv = (1.0f - zg) * ng + zg * h[mi][q];
          h[mi][q] = hv;
          const int seq = mi * 16 + (rq << 2) + q;
          const int hoff = seq * 64 + (jj ^ ((seq & 7) << 3));
          unsigned short hh_ = f2bf(hv);
          dsthi[hoff] = (short)hh_;
          dstlo[hoff] = (short)f2bf(hv - bf2f(hh_));
        }
      }
    }
  }

  // feat = h1(T-1), from layer-1 waves
  if (layer == 1) {
#pragma unroll
    for (int mi = 0; mi < 2; ++mi)
#pragma unroll
      for (int q = 0; q < 4; ++q) {
        const int seq = mi * 16 + (rq << 2) + q;
        feat[(size_t)(gbase + seq) * 64 + jj] = h[mi][q];
      }
  }
}

// ---------------------------------------------------------------------------
// GAT projection (unchanged).
// ---------------------------------------------------------------------------
__global__ __launch_bounds__(256) void gat_feat_kernel(
    const float* __restrict__ feat, const float* __restrict__ gatW,
    const float* __restrict__ a_src, const float* __restrict__ a_dst,
    float* __restrict__ Wh, float* __restrict__ srcv, float* __restrict__ dstv)
{
  __shared__ float sGatW[64 * 128];
  __shared__ float sFeat[8][64];
  __shared__ float sAs[128], sAd[128];
  const int tid = threadIdx.x;
  const int rowbase = blockIdx.x * 8;
  for (int idx = tid; idx < 8192; idx += 256) sGatW[idx] = gatW[idx];
  if (tid < 128) { sAs[tid] = a_src[tid]; sAd[tid] = a_dst[tid]; }
  for (int idx = tid; idx < 512; idx += 256)
    sFeat[idx >> 6][idx & 63] = feat[(size_t)rowbase * 64 + idx];
  __syncthreads();

  const int hf = tid & 127, half = tid >> 7;
  const int h = hf >> 5;
  const float as = sAs[hf], ad = sAd[hf];
  for (int rr = half; rr < 8; rr += 2) {
    float acc = 0.0f;
#pragma unroll 8
    for (int k = 0; k < 64; ++k) acc = fmaf(sFeat[rr][k], sGatW[k * 128 + hf], acc);
    const size_t grow = rowbase + rr;
    Wh[grow * 128 + hf] = acc;
    float ps = acc * as, pd = acc * ad;
#pragma unroll
    for (int m = 16; m >= 1; m >>= 1) {
      ps += __shfl_xor(ps, m, 32);
      pd += __shfl_xor(pd, m, 32);
    }
    if ((hf & 31) == 0) {
      srcv[grow * 4 + h] = ps;
      dstv[grow * 4 + h] = pd;
    }
  }
}

// ---------------------------------------------------------------------------
// Attention + gat aggregation (unchanged from R4).
// ---------------------------------------------------------------------------
__global__ __launch_bounds__(256) void attn_kernel(
    const float* __restrict__ Wh, const float* __restrict__ srcp,
    const float* __restrict__ dstp, const int* __restrict__ adj,
    float* __restrict__ attn_out, float* __restrict__ gat_out)
{
  __shared__ __align__(16) float sDst[4096];          // 16 KB
  __shared__ __align__(16) float sSrc[128];
  __shared__ __align__(16) float sIS[128];            // 1/sum (or -1 sentinel)
  __shared__ unsigned int sAdjW[32][32];              // 4 KB bitmask
  __shared__ __align__(16) unsigned short sPhi[4][32][40];  // 10 KB
  __shared__ __align__(16) unsigned short sPlo[4][32][40];  // 10 KB
  __shared__ __align__(16) unsigned short sBhi[4][32][40];  // 10 KB
  __shared__ __align__(16) unsigned short sBlo[4][32][40];  // 10 KB

  const int tid = threadIdx.x;
  const int bid = blockIdx.x;
  const int swzb = ((bid & 7) << 6) | (bid >> 3);     // XCD-cluster swizzle
  const int b = swzb >> 5;
  const int itile = (swzb & 31) << 5;

  // ---- stage dst, src ----
  for (int idx = tid; idx < 4096; idx += 256) sDst[idx] = dstp[(size_t)b * 4096 + idx];
  if (tid < 128) sSrc[tid] = srcp[((size_t)b * 1024 + itile) * 4 + tid];

  // ---- build adj bitmask: thread -> (row=tid>>3, 4 words) ----
  {
    const int row = tid >> 3;
    const int w0 = (tid & 7) << 2;
    const int* arow_g = adj + (size_t)(itile + row) * 1024 + (w0 << 5);
#pragma unroll
    for (int wq = 0; wq < 4; ++wq) {
      unsigned int word = 0;
#pragma unroll
      for (int c4 = 0; c4 < 8; ++c4) {
        int4 v = *reinterpret_cast<const int4*>(arow_g + (wq << 5) + (c4 << 2));
        word |= (unsigned)((v.x != 0) ? 1 : 0) << (c4 * 4 + 0);
        word |= (unsigned)((v.y != 0) ? 1 : 0) << (c4 * 4 + 1);
        word |= (unsigned)((v.z != 0) ? 1 : 0) << (c4 * 4 + 2);
        word |= (unsigned)((v.w != 0) ? 1 : 0) << (c4 * 4 + 3);
      }
      sAdjW[row][w0 + wq] = word;
    }
  }
  __syncthreads();

  // ---- pass 1: s[i][h] = sum_j mask*exp(leaky(src+dst)), m=0 ----
  {
    const int i = tid >> 3;          // 0..31
    const int par = tid & 7;         // 8-way j split
    const float4 sv = *reinterpret_cast<const float4*>(&sSrc[i * 4]);
    f32x4 acc = (f32x4){0.f, 0.f, 0.f, 0.f};
    const unsigned int bit0 = 1u << par;
    for (int kw = 0; kw < 32; ++kw) {
      const unsigned int word = sAdjW[i][kw];
#pragma unroll
      for (int e = 0; e < 4; ++e) {
        const int gj = (kw << 5) + (e << 3) + par;
        const float4 dv = *reinterpret_cast<const float4*>(&sDst[gj * 4]);
        const float mf = (word & (bit0 << (e << 3))) ? 1.0f : 0.0f;
        acc[0] = fmaf(mf, __expf(leaky02(sv.x + dv.x)), acc[0]);
        acc[1] = fmaf(mf, __expf(leaky02(sv.y + dv.y)), acc[1]);
        acc[2] = fmaf(mf, __expf(leaky02(sv.z + dv.z)), acc[2]);
        acc[3] = fmaf(mf, __expf(leaky02(sv.w + dv.w)), acc[3]);
      }
    }
#pragma unroll
    for (int m = 1; m < 8; m <<= 1) {
#pragma unroll
      for (int q = 0; q < 4; ++q) acc[q] += __shfl_xor(acc[q], m, 64);
    }
    if (par == 0) {
      float4 isv;
      isv.x = acc[0] > 0.f ? 1.0f / acc[0] : -1.0f;
      isv.y = acc[1] > 0.f ? 1.0f / acc[1] : -1.0f;
      isv.z = acc[2] > 0.f ? 1.0f / acc[2] : -1.0f;
      isv.w = acc[3] > 0.f ? 1.0f / acc[3] : -1.0f;
      *reinterpret_cast<float4*>(&sIS[i * 4]) = isv;
    }
  }
  __syncthreads();

  // ---- pass 2: 32 j-tiles of 32 ----
  const int il = tid >> 3;          // 0..31 (i row)
  const int jsub = tid & 7;
  const int wv = tid >> 6;          // wave id = head for MFMA phase
  const int l = tid & 63;
  const int jjB = tid & 31;         // B-staging: Wh row within tile
  const int fcB = tid >> 5;         // B-staging: 16-hf chunk

  const float4 sv4 = *reinterpret_cast<const float4*>(&sSrc[il * 4]);
  const float4 is4 = *reinterpret_cast<const float4*>(&sIS[il * 4]);
  f32x4* arow_out = reinterpret_cast<f32x4*>(
      attn_out + ((size_t)(b * 1024 + itile + il)) * 4096);

  f32x4 accg[2][2];
#pragma unroll
  for (int m = 0; m < 2; ++m)
#pragma unroll
    for (int n = 0; n < 2; ++n) accg[m][n] = (f32x4){0.f, 0.f, 0.f, 0.f};

  // A/B fragment LDS offsets (element index into [32][40] plane)
  const int frow = l & 15, fchunk = l >> 4;
  const int wplane = wv * (32 * 40);

  for (int jt = 0; jt < 32; ++jt) {
    const int j0 = jt << 5;
    // -- compute & write phase --
    {
      const unsigned int word = sAdjW[il][jt];
#pragma unroll
      for (int q = 0; q < 4; ++q) {
        const int j = jsub + (q << 3);
        const int gj = j0 + j;
        const float4 dv = *reinterpret_cast<const float4*>(&sDst[gj * 4]);
        const float mf = (word & (1u << j)) ? 1.0f : 0.0f;
        f32x4 a4;
        float ex;
        ex = mf * __expf(leaky02(sv4.x + dv.x)); a4[0] = ex * is4.x; if (is4.x < 0.f) a4[0] = 9.765625e-4f;
        ex = mf * __expf(leaky02(sv4.y + dv.y)); a4[1] = ex * is4.y; if (is4.y < 0.f) a4[1] = 9.765625e-4f;
        ex = mf * __expf(leaky02(sv4.z + dv.z)); a4[2] = ex * is4.z; if (is4.z < 0.f) a4[2] = 9.765625e-4f;
        ex = mf * __expf(leaky02(sv4.w + dv.w)); a4[3] = ex * is4.w; if (is4.w < 0.f) a4[3] = 9.765625e-4f;
        __builtin_nontemporal_store(a4, &arow_out[gj]);
        float av[4] = {a4[0], a4[1], a4[2], a4[3]};
#pragma unroll
        for (int h = 0; h < 4; ++h) {
          unsigned short hi = f2bf(av[h]);
          sPhi[h][il][j] = hi;
          sPlo[h][il][j] = f2bf(av[h] - bf2f(hi));
        }
      }
      // B staging: Wh[j0+jjB][fcB*16..+16] -> sB[h][f][jjB]
      const float* wrow = Wh + ((size_t)(b * 1024 + j0 + jjB)) * 128 + (fcB << 4);
#pragma unroll
      for (int c4 = 0; c4 < 4; ++c4) {
        float4 v = *reinterpret_cast<const float4*>(wrow + (c4 << 2));
        float vv[4] = {v.x, v.y, v.z, v.w};
#pragma unroll
        for (int e = 0; e < 4; ++e) {
          const int hf = (fcB << 4) + (c4 << 2) + e;
          const int h = hf >> 5, f = hf & 31;
          unsigned short hi = f2bf(vv[e]);
          sBhi[h][f][jjB] = hi;
          sBlo[h][f][jjB] = f2bf(vv[e] - bf2f(hi));
        }
      }
    }
    __syncthreads();
    // -- MFMA phase: wave wv handles head wv --
    {
      short8 ahi[2], alo[2], bhi[2], blo[2];
#pragma unroll
      for (int m = 0; m < 2; ++m) {
        const int ro = wplane + (m * 16 + frow) * 40 + fchunk * 8;
        ahi[m] = *reinterpret_cast<const short8*>(&sPhi[0][0][0] + ro);
        alo[m] = *reinterpret_cast<const short8*>(&sPlo[0][0][0] + ro);
      }
#pragma unroll
      for (int n = 0; n < 2; ++n) {
        const int ro = wplane + (n * 16 + frow) * 40 + fchunk * 8;
        bhi[n] = *reinterpret_cast<const short8*>(&sBhi[0][0][0] + ro);
        blo[n] = *reinterpret_cast<const short8*>(&sBlo[0][0][0] + ro);
      }
#pragma unroll
      for (int m = 0; m < 2; ++m)
#pragma unroll
        for (int n = 0; n < 2; ++n) {
          accg[m][n] = MFMA(ahi[m], bhi[n], accg[m][n]);
          accg[m][n] = MFMA(ahi[m], blo[n], accg[m][n]);
          accg[m][n] = MFMA(alo[m], bhi[n], accg[m][n]);
        }
    }
    __syncthreads();
  }

  // ---- epilogue: elu + store gat ----
#pragma unroll
  for (int m = 0; m < 2; ++m)
#pragma unroll
    for (int n = 0; n < 2; ++n)
#pragma unroll
      for (int q = 0; q < 4; ++q) {
        const int i = m * 16 + (l >> 4) * 4 + q;
        const int f = n * 16 + (l & 15);
        float v = accg[m][n][q];
        v = v > 0.0f ? v : (__expf(v) - 1.0f);
        gat_out[((size_t)(b * 1024 + itile + i)) * 128 + wv * 32 + f] = v;
      }
}

// ---------------------------------------------------------------------------
// MLP chain (unchanged).
// ---------------------------------------------------------------------------
__global__ __launch_bounds__(256) void mlp_kernel(
    const float* __restrict__ gat,
    const float* __restrict__ rW1, const float* __restrict__ rb1,
    const float* __restrict__ rW2, const float* __restrict__ rb2,
    const float* __restrict__ fW,  const float* __restrict__ fb,
    const float* __restrict__ ln_g, const float* __restrict__ ln_b,
    const float* __restrict__ nW1, const float* __restrict__ nb1,
    const float* __restrict__ nW2, const float* __restrict__ nb2,
    float* __restrict__ out)
{
  __shared__ float sW[128 * 128];
  __shared__ float sZ[16][128];
  __shared__ float sT[16][128];
  __shared__ float sY[16][32];
  __shared__ float sT2[16][32];
  __shared__ float sB1[128], sB2[128];

  const int tid = threadIdx.x;
  const int rowbase = blockIdx.x * 16;

  for (int idx = tid; idx < 16384; idx += 256) sW[idx] = rW1[idx];
  if (tid < 128) { sB1[tid] = rb1[tid]; sB2[tid] = rb2[tid]; }
  for (int idx = tid; idx < 2048; idx += 256)
    sZ[idx >> 7][idx & 127] = gat[(size_t)rowbase * 128 + idx];
  __syncthreads();

  const int c = tid & 127, rblk = tid >> 7;
  for (int q = 0; q < 8; ++q) {
    const int r = rblk + (q << 1);
    float a = sB1[c];
#pragma unroll 8
    for (int k = 0; k < 128; ++k) a = fmaf(sZ[r][k], sW[k * 128 + c], a);
    sT[r][c] = a > 0.0f ? a : 0.0f;
  }
  __syncthreads();
  for (int idx = tid; idx < 16384; idx += 256) sW[idx] = rW2[idx];
  __syncthreads();
  for (int q = 0; q < 8; ++q) {
    const int r = rblk + (q << 1);
    float a = sB2[c];
#pragma unroll 8
    for (int k = 0; k < 128; ++k) a = fmaf(sT[r][k], sW[k * 128 + c], a);
    a += sZ[r][c];
    sZ[r][c] = a > 0.0f ? a : 0.0f;
  }
  __syncthreads();
  for (int idx = tid; idx < 4096; idx += 256) sW[idx] = fW[idx];
  for (int idx = tid; idx < 1024; idx += 256) {
    sW[4096 + idx] = nW1[idx];
    sW[5120 + idx] = nW2[idx];
  }
  if (tid < 32) {
    sW[6144 + tid] = fb[tid];
    sW[6176 + tid] = ln_g[tid];
    sW[6208 + tid] = ln_b[tid];
    sW[6240 + tid] = nb1[tid];
    sW[6272 + tid] = nb2[tid];
  }
  __syncthreads();

  const int o = tid & 31, rr2 = tid >> 5;
  for (int g = 0; g < 2; ++g) {
    const int r = rr2 + (g << 3);
    float y = sW[6144 + o];
#pragma unroll 8
    for (int k = 0; k < 128; ++k) y = fmaf(sZ[r][k], sW[k * 32 + o], y);
    float mu = y;
#pragma unroll
    for (int m = 16; m >= 1; m >>= 1) mu += __shfl_xor(mu, m, 32);
    mu *= (1.0f / 32.0f);
    const float d = y - mu;
    float var = d * d;
#pragma unroll
    for (int m = 16; m >= 1; m >>= 1) var += __shfl_xor(var, m, 32);
    var *= (1.0f / 32.0f);
    const float yn = d * rsqrtf(var + 1e-5f) * sW[6176 + o] + sW[6208 + o];
    sY[r][o] = tanhf(yn);
  }
  __syncthreads();
  for (int g = 0; g < 2; ++g) {
    const int r = rr2 + (g << 3);
    float a = sW[6240 + o];
#pragma unroll
    for (int k = 0; k < 32; ++k) a = fmaf(sY[r][k], sW[4096 + k * 32 + o], a);
    sT2[r][o] = a > 0.0f ? a : 0.0f;
  }
  __syncthreads();
  for (int g = 0; g < 2; ++g) {
    const int r = rr2 + (g << 3);
    float a = sW[6272 + o];
#pragma unroll
    for (int k = 0; k < 32; ++k) a = fmaf(sT2[r][k], sW[5120 + k * 32 + o], a);
    out[(size_t)(rowbase + r) * 32 + o] = a;
  }
}

// ---------------------------------------------------------------------------
extern "C" void kernel_launch(void* const* d_in, const int* in_sizes, int n_in,
                              void* d_out, int out_size, void* d_ws, size_t ws_size,
                              hipStream_t stream) {
  const float* seq   = (const float*)d_in[0];
  const int*   adj   = (const int*)d_in[1];
  const float* Wih0  = (const float*)d_in[2];
  const float* Whh0  = (const float*)d_in[3];
  const float* bih0  = (const float*)d_in[4];
  const float* bhh0  = (const float*)d_in[5];
  const float* Wih1  = (const float*)d_in[6];
  const float* Whh1  = (const float*)d_in[7];
  const float* bih1  = (const float*)d_in[8];
  const float* bhh1  = (const float*)d_in[9];
  const float* gatW  = (const float*)d_in[10];
  const float* a_src = (const float*)d_in[11];
  const float* a_dst = (const float*)d_in[12];
  const float* rW1   = (const float*)d_in[13];
  const float* rb1   = (const float*)d_in[14];
  const float* rW2   = (const float*)d_in[15];
  const float* rb2   = (const float*)d_in[16];
  const float* fW    = (const float*)d_in[17];
  const float* fb    = (const float*)d_in[18];
  const float* ln_g  = (const float*)d_in[19];
  const float* ln_b  = (const float*)d_in[20];
  const float* nW1   = (const float*)d_in[21];
  const float* nb1   = (const float*)d_in[22];
  const float* nW2   = (const float*)d_in[23];
  const float* nb2   = (const float*)d_in[24];

  float* out  = (float*)d_out;                  // [BN][32] at offset 0
  float* attn = out + (size_t)BN * OO;          // [B,N,N,4] region (268MB)

  float* ws   = (float*)d_ws;
  float* feat = ws;                             // [BN][64]
  float* Wh   = feat + (size_t)BN * 64;         // [BN][128]
  float* srcv = Wh + (size_t)BN * 128;          // [BN][4]
  float* dstv = srcv + (size_t)BN * 4;          // [BN][4]
  float* gat  = dstv + (size_t)BN * 4;          // [BN][128]

  gru_fused_kernel<<<512, 512, 0, stream>>>(seq, Wih0, Whh0, bih0, bhh0,
                                            Wih1, Whh1, bih1, bhh1, feat);
  gat_feat_kernel<<<2048, 256, 0, stream>>>(feat, gatW, a_src, a_dst, Wh, srcv, dstv);
  attn_kernel<<<512, 256, 0, stream>>>(Wh, srcv, dstv, adj, attn, gat);
  mlp_kernel<<<1024, 256, 0, stream>>>(gat, rW1, rb1, rW2, rb2, fW, fb,
                                       ln_g, ln_b, nW1, nb1, nW2, nb2, out);
}